// Round 4
// baseline (79.180 us; speedup 1.0000x reference)
//
#include <hip/hip_runtime.h>

#define RCUT 6.0f

typedef _Float16 h2 __attribute__((ext_vector_type(2)));

__device__ __forceinline__ float fast_tanh(float x) {
    float e = __expf(2.0f * x);              // inf for large x -> tanh=1
    return 1.0f - 2.0f * __builtin_amdgcn_rcpf(e + 1.0f);
}

#if __has_builtin(__builtin_amdgcn_fdot2)
__device__ __forceinline__ float dot2(h2 a, h2 b, float c) {
    return __builtin_amdgcn_fdot2(a, b, c, false);
}
#else
__device__ __forceinline__ float dot2(h2 a, h2 b, float c) {
    return (float)a.x * (float)b.x + (float)a.y * (float)b.y + c;
}
#endif

__device__ __forceinline__ h2 pkh(float a, float b) {
#if __has_builtin(__builtin_amdgcn_cvt_pkrtz)
    union { __fp16 __attribute__((ext_vector_type(2))) r; h2 h; } u;
    u.r = __builtin_amdgcn_cvt_pkrtz(a, b);
    return u.h;
#else
    h2 r; r.x = (_Float16)a; r.y = (_Float16)b; return r;
#endif
}

// ---------------- Kernel 1: per-atom neighbor scan + embed MLP + G + Feat ----
// 256 threads = 4 waves. Stage 1: thread = (pair p = tid&127, c-half = tid>>7).
// Stage 2: thread = (k = tid>>6, c = tid&63).
__global__ __launch_bounds__(256, 4) void k_embed(
    const float* __restrict__ coord, const float* __restrict__ box,
    const float* __restrict__ srmean, const float* __restrict__ srstd,
    const float* __restrict__ xrsrstd, const float* __restrict__ Gbias,
    const float* __restrict__ eW0, const float* __restrict__ eb0,
    const float* __restrict__ eW1, const float* __restrict__ eb1,
    const float* __restrict__ eW2, const float* __restrict__ eb2,
    const int* __restrict__ n1p, float* __restrict__ feat, int N)
{
    const int n   = blockIdx.x;
    const int tid = threadIdx.x;
    const int n1  = *n1p;
    const int ti  = (n >= n1) ? 1 : 0;

    __shared__ struct {
        float    w0[2][16], b0[2][16];
        _Float16 w1t[2][32][16];     // [j][g][f]  (16B-aligned rows)
        float    b1[2][32];
        _Float16 w2t[2][64][32];     // [j][c][g]  (64B rows)
        float    b2[2][64];
    } sw;
    __shared__ h2 s_e2[128][33];     // e tile, fp16, padded rows
    __shared__ float s_coef[4][128]; // srbias, Rx, Ry, Rz per pair
    __shared__ unsigned short s_nbr[512];
    __shared__ float s_g4[256];      // G[4][64]
    __shared__ int   s_wcnt[4];

    // ---- weight staging (fp16 for W1/W2, transposed) ----
    for (int t = tid; t < 32; t += 256) { int j = t >> 4, f = t & 15;
        sw.w0[j][f] = eW0[(2 * ti + j) * 16 + f];
        sw.b0[j][f] = eb0[(2 * ti + j) * 16 + f]; }
    for (int t = tid; t < 1024; t += 256) { int j = t >> 9, r = t & 511, f = r >> 5, g = r & 31;
        sw.w1t[j][g][f] = (_Float16)eW1[(2 * ti + j) * 512 + f * 32 + g]; }
    for (int t = tid; t < 64; t += 256) { int j = t >> 5, g = t & 31;
        sw.b1[j][g] = eb1[(2 * ti + j) * 32 + g]; }
    for (int t = tid; t < 4096; t += 256) { int j = t >> 11, r = t & 2047, g = r >> 6, c = r & 63;
        sw.w2t[j][c][g] = (_Float16)eW2[(2 * ti + j) * 2048 + g * 64 + c]; }
    for (int t = tid; t < 128; t += 256) { int j = t >> 6, c = t & 63;
        sw.b2[j][c] = eb2[(2 * ti + j) * 64 + c]; }

    const float Lx = box[0], Ly = box[4], Lz = box[8];
    const float iLx = 1.0f / Lx, iLy = 1.0f / Ly, iLz = 1.0f / Lz;
    const float xn = coord[n], yn = coord[N + n], zn = coord[2 * N + n];

    // ---- parallel deterministic neighbor scan (all 4 waves, m ascending) ----
    const int wid = tid >> 6, lane = tid & 63;
    {
        unsigned long long bal[4];
        int wtotal = 0;
        const int mystart = wid * 256;
        #pragma unroll
        for (int r = 0; r < 4; r++) {
            int m = mystart + r * 64 + lane;
            float dx = coord[m] - xn;         dx -= Lx * rintf(dx * iLx);
            float dy = coord[N + m] - yn;     dy -= Ly * rintf(dy * iLy);
            float dz = coord[2 * N + m] - zn; dz -= Lz * rintf(dz * iLz);
            float r2 = dx * dx + dy * dy + dz * dz;
            bool pred = (r2 < RCUT * RCUT) && (m != n);
            bal[r] = __ballot(pred);
            wtotal += (int)__popcll(bal[r]);
        }
        if (lane == 0) s_wcnt[wid] = wtotal;
        __syncthreads();
        int base = 0;
        for (int w = 0; w < wid; w++) base += s_wcnt[w];
        #pragma unroll
        for (int r = 0; r < 4; r++) {
            bool pred = (bal[r] >> lane) & 1ull;
            int pos = (int)__popcll(bal[r] & ((1ull << lane) - 1ull));
            if (pred && (base + pos) < 512)
                s_nbr[base + pos] = (unsigned short)(wid * 256 + r * 64 + lane);
            base += (int)__popcll(bal[r]);
        }
    }
    __syncthreads();
    int cnt = s_wcnt[0] + s_wcnt[1] + s_wcnt[2] + s_wcnt[3];
    if (cnt > 512) cnt = 512;

    const float srm  = srmean[ti];
    const float isrs = 1.0f / srstd[ti];
    const float ixrs = 1.0f / xrsrstd[ti];

    const int p  = tid & 127;   // stage-1 pair slot
    const int hh = tid >> 7;    // stage-1 c-half
    const int k2 = tid >> 6;    // stage-2 k
    const int c2 = tid & 63;    // stage-2 c
    const int dummy = (n + 1 < N) ? (n + 1) : 0;

    float acc0 = 0.0f, acc1 = 0.0f;

    const int ntiles = (cnt + 127) >> 7;
    for (int t = 0; t < ntiles; t++) {
        __syncthreads();   // protect s_e2/s_coef from previous stage-2 readers
        {   // ---- stage 1: per-pair MLP -> s_e2 (my 32 c's), coeffs -> s_coef
            const int pi = (t << 7) + p;
            const bool valid = pi < cnt;
            int m = valid ? (int)s_nbr[pi] : dummy;
            float dx = coord[m] - xn;         dx -= Lx * rintf(dx * iLx);
            float dy = coord[N + m] - yn;     dy -= Ly * rintf(dy * iLy);
            float dz = coord[2 * N + m] - zn; dz -= Lz * rintf(dz * iLz);
            float r2 = dx * dx + dy * dy + dz * dz;
            float r  = sqrtf(r2);
            float rinv = __builtin_amdgcn_rcpf(r);
            float u  = r * (1.0f / RCUT);
            float u3 = u * u * u;
            float sw_ = ((-6.0f * u + 15.0f) * u - 10.0f) * u3 + 1.0f;
            if (!valid) sw_ = 0.0f;
            float sr  = sw_ * rinv;
            float srn = (sr - srm) * isrs;
            if (hh == 0) {
                float csr = valid ? sr * isrs : 0.0f;
                float crs = valid ? (sr * rinv * ixrs + 1e-15f) : 0.0f;
                s_coef[0][p] = csr;
                s_coef[1][p] = crs * dx;
                s_coef[2][p] = crs * dy;
                s_coef[3][p] = crs * dz;
            }

            const int j = (m >= n1) ? 1 : 0;
            // W0: 1 -> 16
            float h0[16];
            #pragma unroll
            for (int f = 0; f < 16; f++)
                h0[f] = fast_tanh(fmaf(srn, sw.w0[j][f], sw.b0[j][f]));
            h2 h0p[8];
            #pragma unroll
            for (int q = 0; q < 8; q++) h0p[q] = pkh(h0[2 * q], h0[2 * q + 1]);

            // W1: 16 -> 32 (dot2)
            h2 h1p[16];
            #pragma unroll
            for (int g2 = 0; g2 < 16; g2++) {
                float hv[2];
                #pragma unroll
                for (int u_ = 0; u_ < 2; u_++) {
                    int g = 2 * g2 + u_;
                    union { float4 f4; h2 h[4]; } wa, wb;
                    wa.f4 = *(const float4*)&sw.w1t[j][g][0];
                    wb.f4 = *(const float4*)&sw.w1t[j][g][8];
                    float a = sw.b1[j][g];
                    #pragma unroll
                    for (int q = 0; q < 4; q++) a = dot2(h0p[q], wa.h[q], a);
                    #pragma unroll
                    for (int q = 0; q < 4; q++) a = dot2(h0p[4 + q], wb.h[q], a);
                    hv[u_] = fast_tanh(a);
                }
                h1p[g2] = pkh(hv[0], hv[1]);
            }

            // W2: 32 -> my 32 of 64 c's (dot2), store fp16 pairs
            const int cbase = hh * 32;
            #pragma unroll 2
            for (int cc = 0; cc < 32; cc += 2) {
                float ev[2];
                #pragma unroll
                for (int u_ = 0; u_ < 2; u_++) {
                    int c = cbase + cc + u_;
                    union { float4 f4; h2 h[4]; } w[4];
                    const float4* wp = (const float4*)&sw.w2t[j][c][0];
                    w[0].f4 = wp[0]; w[1].f4 = wp[1]; w[2].f4 = wp[2]; w[3].f4 = wp[3];
                    float a = sw.b2[j][c];
                    #pragma unroll
                    for (int q = 0; q < 16; q++) a = dot2(h1p[q], w[q >> 2].h[q & 3], a);
                    ev[u_] = fast_tanh(a);
                }
                s_e2[p][(cbase + cc) >> 1] = pkh(ev[0], ev[1]);
            }
        }
        __syncthreads();
        // ---- stage 2: acc[k][c] += coeff[k][nb] * e[nb][c]
        const int tc = min(128, cnt - (t << 7));
        const _Float16* eh = (const _Float16*)&s_e2[0][0];
        const float* cf = &s_coef[k2][0];
        int nb = 0;
        for (; nb + 1 < tc; nb += 2) {
            acc0 = fmaf(cf[nb],     (float)eh[nb * 66 + c2],       acc0);
            acc1 = fmaf(cf[nb + 1], (float)eh[(nb + 1) * 66 + c2], acc1);
        }
        if (nb < tc) acc0 = fmaf(cf[nb], (float)eh[nb * 66 + c2], acc0);
    }

    // ---- epilogue: G then Feat
    {
        float gv = (acc0 + acc1) * (1.0f / 64.0f);
        if (k2 == 0) gv += Gbias[c2];
        s_g4[k2 * 64 + c2] = gv;
    }
    __syncthreads();
    {
        float* out = feat + (size_t)n * 1024;
        #pragma unroll
        for (int q = 0; q < 4; q++) {
            int o = tid + 256 * q;
            int a = o >> 6, c = o & 63;       // a uniform per wave, c = lane
            float s = s_g4[a] * s_g4[c];
            s = fmaf(s_g4[64 + a],  s_g4[64 + c],  s);
            s = fmaf(s_g4[128 + a], s_g4[128 + c], s);
            s = fmaf(s_g4[192 + a], s_g4[192 + c], s);
            out[o] = s;
        }
    }
}

// ---------------- Kernel 2: fit net (2 atoms / block, 512 thr, K-split 4) ----
__global__ __launch_bounds__(512, 4) void k_fit(
    const float* __restrict__ feat,
    const float* __restrict__ W0, const float* __restrict__ b0,
    const float* __restrict__ W1, const float* __restrict__ b1,
    const float* __restrict__ W2, const float* __restrict__ b2,
    const float* __restrict__ Ebias, const int* __restrict__ n1p,
    float* __restrict__ out)
{
    __shared__ float s_f[2][1024];
    __shared__ float s_red[2][4][128];
    __shared__ float s_h[2][128];
    __shared__ float s_h1[2][128];
    __shared__ float s_part[4];
    const int tid = threadIdx.x;
    const int n0 = blockIdx.x * 2;
    const int n1 = *n1p;
    const int a  = tid >> 8;           // atom slot 0..1
    const int r_ = tid & 255;
    const int fp = r_ & 63;            // f-pair: f = 2fp, 2fp+1
    const int ks = r_ >> 6;            // K-split 0..3
    const int ia = (n0 + a >= n1) ? 1 : 0;

    {   // stage feat rows (vectorized): 2048 floats = 512 float4
        const float4* src = (const float4*)(feat + (size_t)n0 * 1024);
        ((float4*)&s_f[0][0])[tid] = src[tid];
    }
    __syncthreads();

    // ---- layer 0: 1024 -> 128 (f-pair columns, K-split 4) ----
    {
        const float* wp = W0 + (size_t)ia * 131072 + 2 * fp;
        const float* fr = &s_f[a][0];
        float a0 = 0.f, a1 = 0.f;
        const int x0 = ks * 256;
        #pragma unroll 8
        for (int x = x0; x < x0 + 256; x++) {
            float2 w = *(const float2*)(wp + (size_t)x * 128);
            float fv = fr[x];
            a0 = fmaf(fv, w.x, a0);
            a1 = fmaf(fv, w.y, a1);
        }
        s_red[a][ks][2 * fp]     = a0;
        s_red[a][ks][2 * fp + 1] = a1;
    }
    __syncthreads();
    if (tid < 256) {
        int aa = tid >> 7, f = tid & 127;
        int iaa = (n0 + aa >= n1) ? 1 : 0;
        float s = (s_red[aa][0][f] + s_red[aa][1][f]) +
                  (s_red[aa][2][f] + s_red[aa][3][f]) + b0[iaa * 128 + f];
        s_h[aa][f] = fast_tanh(s);
    }
    __syncthreads();

    // ---- layer 1: 128 -> 128 (f-pair columns, K-split 4) ----
    {
        const float* wp = W1 + (size_t)ia * 16384 + 2 * fp;
        const float* hr = &s_h[a][0];
        float a0 = 0.f, a1 = 0.f;
        const int g0 = ks * 32;
        #pragma unroll 8
        for (int g = g0; g < g0 + 32; g++) {
            float2 w = *(const float2*)(wp + (size_t)g * 128);
            float hv = hr[g];
            a0 = fmaf(hv, w.x, a0);
            a1 = fmaf(hv, w.y, a1);
        }
        s_red[a][ks][2 * fp]     = a0;
        s_red[a][ks][2 * fp + 1] = a1;
    }
    __syncthreads();
    if (tid < 256) {
        int aa = tid >> 7, f = tid & 127;
        int iaa = (n0 + aa >= n1) ? 1 : 0;
        float s = (s_red[aa][0][f] + s_red[aa][1][f]) +
                  (s_red[aa][2][f] + s_red[aa][3][f]) + b1[iaa * 128 + f];
        s_h1[aa][f] = fast_tanh(s);
    }
    __syncthreads();

    // ---- layer 2 + reduction ----
    if (tid < 256) {
        int aa = tid >> 7, f = tid & 127;
        int iaa = (n0 + aa >= n1) ? 1 : 0;
        float pv = s_h1[aa][f] * W2[iaa * 128 + f];
        #pragma unroll
        for (int m = 1; m < 64; m <<= 1) pv += __shfl_xor(pv, m);
        if ((tid & 63) == 0) s_part[tid >> 6] = pv;
    }
    __syncthreads();
    if (tid == 0) {
        int i0 = (n0 >= n1) ? 1 : 0;
        int i1 = (n0 + 1 >= n1) ? 1 : 0;
        float e0 = s_part[0] + s_part[1] + b2[i0] + Ebias[i0];
        float e1 = s_part[2] + s_part[3] + b2[i1] + Ebias[i1];
        atomicAdd(out, e0 + e1);
    }
}

extern "C" void kernel_launch(void* const* d_in, const int* in_sizes, int n_in,
                              void* d_out, int out_size, void* d_ws, size_t ws_size,
                              hipStream_t stream) {
    const float* coord   = (const float*)d_in[0];
    const float* box     = (const float*)d_in[1];
    const float* srmean  = (const float*)d_in[2];
    const float* srstd   = (const float*)d_in[3];
    const float* xrsrstd = (const float*)d_in[4];
    const float* Gbias   = (const float*)d_in[5];
    const float* Ebias   = (const float*)d_in[6];
    const float* eW0     = (const float*)d_in[7];
    const float* eb0     = (const float*)d_in[8];
    const float* eW1     = (const float*)d_in[9];
    const float* eb1     = (const float*)d_in[10];
    const float* eW2     = (const float*)d_in[11];
    const float* eb2     = (const float*)d_in[12];
    const float* fW0     = (const float*)d_in[13];
    const float* fb0     = (const float*)d_in[14];
    const float* fW1     = (const float*)d_in[15];
    const float* fb1     = (const float*)d_in[16];
    const float* fW2     = (const float*)d_in[17];
    const float* fb2     = (const float*)d_in[18];
    const int*   n1p     = (const int*)d_in[19];

    const int N = in_sizes[0] / 3;          // 1024
    float* featbuf = (float*)d_ws;          // N*1024 f32 = 4 MB

    (void)hipMemsetAsync(d_out, 0, sizeof(float), stream);
    k_embed<<<N, 256, 0, stream>>>(coord, box, srmean, srstd, xrsrstd, Gbias,
                                   eW0, eb0, eW1, eb1, eW2, eb2, n1p, featbuf, N);
    k_fit<<<N / 2, 512, 0, stream>>>(featbuf, fW0, fb0, fW1, fb1, fW2, fb2,
                                     Ebias, n1p, (float*)d_out);
}

// Round 5
// 63.585 us; speedup vs baseline: 1.2452x; 1.2452x over previous
//
#include <hip/hip_runtime.h>

#define RCUT 6.0f

typedef _Float16 h2 __attribute__((ext_vector_type(2)));

__device__ __forceinline__ float fast_tanh(float x) {
    float e = __expf(2.0f * x);              // inf for large x -> tanh=1
    return 1.0f - 2.0f * __builtin_amdgcn_rcpf(e + 1.0f);
}

#if __has_builtin(__builtin_amdgcn_fdot2)
__device__ __forceinline__ float dot2(h2 a, h2 b, float c) {
    return __builtin_amdgcn_fdot2(a, b, c, false);
}
#else
__device__ __forceinline__ float dot2(h2 a, h2 b, float c) {
    return (float)a.x * (float)b.x + (float)a.y * (float)b.y + c;
}
#endif

__device__ __forceinline__ h2 pkh(float a, float b) {
#if __has_builtin(__builtin_amdgcn_cvt_pkrtz)
    union { __fp16 __attribute__((ext_vector_type(2))) r; h2 h; } u;
    u.r = __builtin_amdgcn_cvt_pkrtz(a, b);
    return u.h;
#else
    h2 r; r.x = (_Float16)a; r.y = (_Float16)b; return r;
#endif
}

// ---------------- Kernel 1: per-atom neighbor scan + embed MLP + G + Feat ----
// 256 threads = 4 waves. Stage 1: thread = (pair p = tid&127, c-half = tid>>7).
// Stage 2: thread = (k = tid>>6, c = tid&63).
__global__ __launch_bounds__(256, 4) void k_embed(
    const float* __restrict__ coord, const float* __restrict__ box,
    const float* __restrict__ srmean, const float* __restrict__ srstd,
    const float* __restrict__ xrsrstd, const float* __restrict__ Gbias,
    const float* __restrict__ eW0, const float* __restrict__ eb0,
    const float* __restrict__ eW1, const float* __restrict__ eb1,
    const float* __restrict__ eW2, const float* __restrict__ eb2,
    const int* __restrict__ n1p, h2* __restrict__ feat, int N)
{
    const int n   = blockIdx.x;
    const int tid = threadIdx.x;
    const int n1  = *n1p;
    const int ti  = (n >= n1) ? 1 : 0;

    __shared__ struct {
        float    w0[2][16], b0[2][16];
        _Float16 w1t[2][32][16];     // [j][g][f]  (16B-aligned rows)
        float    b1[2][32];
        _Float16 w2t[2][64][32];     // [j][c][g]  (64B rows)
        float    b2[2][64];
    } sw;
    __shared__ h2 s_e2[128][33];     // e tile, fp16, padded rows
    __shared__ float s_coef[4][128]; // srbias, Rx, Ry, Rz per pair
    __shared__ unsigned short s_nbr[512];
    __shared__ float s_g4[256];      // G[4][64]
    __shared__ int   s_wcnt[4];

    // ---- weight staging (fp16 for W1/W2, transposed) ----
    for (int t = tid; t < 32; t += 256) { int j = t >> 4, f = t & 15;
        sw.w0[j][f] = eW0[(2 * ti + j) * 16 + f];
        sw.b0[j][f] = eb0[(2 * ti + j) * 16 + f]; }
    for (int t = tid; t < 1024; t += 256) { int j = t >> 9, r = t & 511, f = r >> 5, g = r & 31;
        sw.w1t[j][g][f] = (_Float16)eW1[(2 * ti + j) * 512 + f * 32 + g]; }
    for (int t = tid; t < 64; t += 256) { int j = t >> 5, g = t & 31;
        sw.b1[j][g] = eb1[(2 * ti + j) * 32 + g]; }
    for (int t = tid; t < 4096; t += 256) { int j = t >> 11, r = t & 2047, g = r >> 6, c = r & 63;
        sw.w2t[j][c][g] = (_Float16)eW2[(2 * ti + j) * 2048 + g * 64 + c]; }
    for (int t = tid; t < 128; t += 256) { int j = t >> 6, c = t & 63;
        sw.b2[j][c] = eb2[(2 * ti + j) * 64 + c]; }

    const float Lx = box[0], Ly = box[4], Lz = box[8];
    const float iLx = 1.0f / Lx, iLy = 1.0f / Ly, iLz = 1.0f / Lz;
    const float xn = coord[n], yn = coord[N + n], zn = coord[2 * N + n];

    // ---- parallel deterministic neighbor scan (all 4 waves, m ascending) ----
    const int wid = tid >> 6, lane = tid & 63;
    {
        unsigned long long bal[4];
        int wtotal = 0;
        const int mystart = wid * 256;
        #pragma unroll
        for (int r = 0; r < 4; r++) {
            int m = mystart + r * 64 + lane;
            float dx = coord[m] - xn;         dx -= Lx * rintf(dx * iLx);
            float dy = coord[N + m] - yn;     dy -= Ly * rintf(dy * iLy);
            float dz = coord[2 * N + m] - zn; dz -= Lz * rintf(dz * iLz);
            float r2 = dx * dx + dy * dy + dz * dz;
            bool pred = (r2 < RCUT * RCUT) && (m != n);
            bal[r] = __ballot(pred);
            wtotal += (int)__popcll(bal[r]);
        }
        if (lane == 0) s_wcnt[wid] = wtotal;
        __syncthreads();
        int base = 0;
        for (int w = 0; w < wid; w++) base += s_wcnt[w];
        #pragma unroll
        for (int r = 0; r < 4; r++) {
            bool pred = (bal[r] >> lane) & 1ull;
            int pos = (int)__popcll(bal[r] & ((1ull << lane) - 1ull));
            if (pred && (base + pos) < 512)
                s_nbr[base + pos] = (unsigned short)(wid * 256 + r * 64 + lane);
            base += (int)__popcll(bal[r]);
        }
    }
    __syncthreads();
    int cnt = s_wcnt[0] + s_wcnt[1] + s_wcnt[2] + s_wcnt[3];
    if (cnt > 512) cnt = 512;

    const float srm  = srmean[ti];
    const float isrs = 1.0f / srstd[ti];
    const float ixrs = 1.0f / xrsrstd[ti];

    const int p  = tid & 127;   // stage-1 pair slot
    const int hh = tid >> 7;    // stage-1 c-half
    const int k2 = tid >> 6;    // stage-2 k
    const int c2 = tid & 63;    // stage-2 c
    const int dummy = (n + 1 < N) ? (n + 1) : 0;

    float acc0 = 0.0f, acc1 = 0.0f;

    const int ntiles = (cnt + 127) >> 7;
    for (int t = 0; t < ntiles; t++) {
        __syncthreads();   // protect s_e2/s_coef from previous stage-2 readers
        {   // ---- stage 1: per-pair MLP -> s_e2 (my 32 c's), coeffs -> s_coef
            const int pi = (t << 7) + p;
            const bool valid = pi < cnt;
            int m = valid ? (int)s_nbr[pi] : dummy;
            float dx = coord[m] - xn;         dx -= Lx * rintf(dx * iLx);
            float dy = coord[N + m] - yn;     dy -= Ly * rintf(dy * iLy);
            float dz = coord[2 * N + m] - zn; dz -= Lz * rintf(dz * iLz);
            float r2 = dx * dx + dy * dy + dz * dz;
            float r  = sqrtf(r2);
            float rinv = __builtin_amdgcn_rcpf(r);
            float u  = r * (1.0f / RCUT);
            float u3 = u * u * u;
            float sw_ = ((-6.0f * u + 15.0f) * u - 10.0f) * u3 + 1.0f;
            if (!valid) sw_ = 0.0f;
            float sr  = sw_ * rinv;
            float srn = (sr - srm) * isrs;
            if (hh == 0) {
                float csr = valid ? sr * isrs : 0.0f;
                float crs = valid ? (sr * rinv * ixrs + 1e-15f) : 0.0f;
                s_coef[0][p] = csr;
                s_coef[1][p] = crs * dx;
                s_coef[2][p] = crs * dy;
                s_coef[3][p] = crs * dz;
            }

            const int j = (m >= n1) ? 1 : 0;
            // W0: 1 -> 16
            float h0[16];
            #pragma unroll
            for (int f = 0; f < 16; f++)
                h0[f] = fast_tanh(fmaf(srn, sw.w0[j][f], sw.b0[j][f]));
            h2 h0p[8];
            #pragma unroll
            for (int q = 0; q < 8; q++) h0p[q] = pkh(h0[2 * q], h0[2 * q + 1]);

            // W1: 16 -> 32 (dot2)
            h2 h1p[16];
            #pragma unroll
            for (int g2 = 0; g2 < 16; g2++) {
                float hv[2];
                #pragma unroll
                for (int u_ = 0; u_ < 2; u_++) {
                    int g = 2 * g2 + u_;
                    union { float4 f4; h2 h[4]; } wa, wb;
                    wa.f4 = *(const float4*)&sw.w1t[j][g][0];
                    wb.f4 = *(const float4*)&sw.w1t[j][g][8];
                    float a = sw.b1[j][g];
                    #pragma unroll
                    for (int q = 0; q < 4; q++) a = dot2(h0p[q], wa.h[q], a);
                    #pragma unroll
                    for (int q = 0; q < 4; q++) a = dot2(h0p[4 + q], wb.h[q], a);
                    hv[u_] = fast_tanh(a);
                }
                h1p[g2] = pkh(hv[0], hv[1]);
            }

            // W2: 32 -> my 32 of 64 c's (dot2), store fp16 pairs
            const int cbase = hh * 32;
            #pragma unroll 2
            for (int cc = 0; cc < 32; cc += 2) {
                float ev[2];
                #pragma unroll
                for (int u_ = 0; u_ < 2; u_++) {
                    int c = cbase + cc + u_;
                    union { float4 f4; h2 h[4]; } w[4];
                    const float4* wp = (const float4*)&sw.w2t[j][c][0];
                    w[0].f4 = wp[0]; w[1].f4 = wp[1]; w[2].f4 = wp[2]; w[3].f4 = wp[3];
                    float a = sw.b2[j][c];
                    #pragma unroll
                    for (int q = 0; q < 16; q++) a = dot2(h1p[q], w[q >> 2].h[q & 3], a);
                    ev[u_] = fast_tanh(a);
                }
                s_e2[p][(cbase + cc) >> 1] = pkh(ev[0], ev[1]);
            }
        }
        __syncthreads();
        // ---- stage 2: acc[k][c] += coeff[k][nb] * e[nb][c]
        const int tc = min(128, cnt - (t << 7));
        const _Float16* eh = (const _Float16*)&s_e2[0][0];
        const float* cf = &s_coef[k2][0];
        int nb = 0;
        for (; nb + 1 < tc; nb += 2) {
            acc0 = fmaf(cf[nb],     (float)eh[nb * 66 + c2],       acc0);
            acc1 = fmaf(cf[nb + 1], (float)eh[(nb + 1) * 66 + c2], acc1);
        }
        if (nb < tc) acc0 = fmaf(cf[nb], (float)eh[nb * 66 + c2], acc0);
    }

    // ---- epilogue: G then Feat (fp16 packed)
    {
        float gv = (acc0 + acc1) * (1.0f / 64.0f);
        if (k2 == 0) gv += Gbias[c2];
        s_g4[k2 * 64 + c2] = gv;
    }
    __syncthreads();
    {
        h2* outp = feat + (size_t)n * 512;
        #pragma unroll
        for (int q = 0; q < 2; q++) {
            int o2 = tid + 256 * q;          // h2 index; elements 2*o2, 2*o2+1
            int a = o2 >> 5;                 // = (2*o2)>>6
            int c = (2 * o2) & 63;
            float ga0 = s_g4[a],       ga1 = s_g4[64 + a];
            float ga2 = s_g4[128 + a], ga3 = s_g4[192 + a];
            float s0 = ga0 * s_g4[c];
            s0 = fmaf(ga1, s_g4[64 + c],  s0);
            s0 = fmaf(ga2, s_g4[128 + c], s0);
            s0 = fmaf(ga3, s_g4[192 + c], s0);
            float s1 = ga0 * s_g4[c + 1];
            s1 = fmaf(ga1, s_g4[64 + c + 1],  s1);
            s1 = fmaf(ga2, s_g4[128 + c + 1], s1);
            s1 = fmaf(ga3, s_g4[192 + c + 1], s1);
            outp[o2] = pkh(s0, s1);
        }
    }
}

// ---------------- Kernel 2: fit net, LDS-tiled fp16 GEMM (4 atoms / block) ---
// 512 thr: (fp = tid&63 -> cols 2fp,2fp+1; ks2 = (tid>>6)&1 -> K-half; a = tid>>7)
__global__ __launch_bounds__(512) void k_fit(
    const h2* __restrict__ feat,
    const float* __restrict__ W0, const float* __restrict__ b0,
    const float* __restrict__ W1, const float* __restrict__ b1,
    const float* __restrict__ W2, const float* __restrict__ b2,
    const float* __restrict__ Ebias, const int* __restrict__ n1p,
    float* __restrict__ out)
{
    __shared__ h2    s_W[128][64];     // weight tile fp16: [row][col-pair] (32 KB)
    __shared__ h2    s_fd[4][1024];    // feat, each value duplicated in both lanes (16 KB)
    __shared__ float s_red[2][4][128]; // K-split partials (4 KB)
    __shared__ h2    s_hd[4][128];     // layer-0 output, duplicated (2 KB)
    __shared__ float s_h1[4][128];
    __shared__ float s_part[8];

    const int tid = threadIdx.x;
    const int n0  = blockIdx.x * 4;
    const int n1  = *n1p;
    const int ia  = (n0 >= n1) ? 1 : 0;   // block is type-uniform (n1 % 4 == 0)

    const int fp  = tid & 63;
    const int ks2 = (tid >> 6) & 1;
    const int a   = tid >> 7;

    // ---- stage feat rows (4 atoms), duplicating each fp16 into both h2 lanes
    {
        const unsigned int* src = (const unsigned int*)(feat + (size_t)n0 * 512);
        #pragma unroll
        for (int q = 0; q < 4; q++) {
            int idx = tid + 512 * q;            // 0..2047 = (atom, x-pair)
            union { unsigned int u; h2 h; } cv; cv.u = src[idx];
            int aa = idx >> 9, xp = idx & 511;
            h2 lo; lo.x = cv.h.x; lo.y = cv.h.x;
            h2 hi; hi.x = cv.h.y; hi.y = cv.h.y;
            s_fd[aa][2 * xp]     = lo;
            s_fd[aa][2 * xp + 1] = hi;
        }
    }

    // ---- layer 0: 1024 -> 128 over 8 LDS tiles of 128 rows ----
    const float2* wsrc = (const float2*)(W0 + (size_t)ia * 131072);
    float2 pre[16];
    #pragma unroll
    for (int q = 0; q < 16; q++) pre[q] = wsrc[tid + 512 * q];   // tile 0

    float af0 = 0.0f, af1 = 0.0f;
    for (int kt = 0; kt < 8; kt++) {
        __syncthreads();                       // prev tile's readers done / fd visible
        #pragma unroll
        for (int q = 0; q < 16; q++) {
            int i = tid + 512 * q;             // i = xx*64 + fp
            ((h2*)s_W)[i] = pkh(pre[q].x, pre[q].y);
        }
        if (kt < 7) {
            #pragma unroll
            for (int q = 0; q < 16; q++) pre[q] = wsrc[(kt + 1) * 8192 + tid + 512 * q];
        }
        __syncthreads();                       // tile visible
        const int x0 = ks2 * 64, xg = kt * 128 + x0;
        h2 acc2; acc2.x = (_Float16)0.0f; acc2.y = (_Float16)0.0f;
        #pragma unroll
        for (int xx = 0; xx < 64; xx++) {
            h2 w = s_W[x0 + xx][fp];
            h2 f = s_fd[a][xg + xx];           // wave-uniform broadcast
            acc2 += w * f;                     // v_pk_fma_f16
        }
        af0 += (float)acc2.x;
        af1 += (float)acc2.y;
    }
    s_red[ks2][a][2 * fp]     = af0;
    s_red[ks2][a][2 * fp + 1] = af1;
    __syncthreads();
    {
        int f = tid & 127, aa = tid >> 7;
        int iaa = (n0 + aa >= n1) ? 1 : 0;
        float h = fast_tanh(s_red[0][aa][f] + s_red[1][aa][f] + b0[iaa * 128 + f]);
        h2 d; d.x = (_Float16)h; d.y = d.x;
        s_hd[aa][f] = d;
    }
    __syncthreads();

    // ---- layer 1: 128 -> 128 (reuse s_W for the W1 tile) ----
    {
        const float2* w1src = (const float2*)(W1 + (size_t)ia * 16384);
        float2 p1[16];
        #pragma unroll
        for (int q = 0; q < 16; q++) p1[q] = w1src[tid + 512 * q];
        #pragma unroll
        for (int q = 0; q < 16; q++) {
            int i = tid + 512 * q;
            ((h2*)s_W)[i] = pkh(p1[q].x, p1[q].y);
        }
    }
    __syncthreads();
    {
        const int g0 = ks2 * 64;
        h2 acc2; acc2.x = (_Float16)0.0f; acc2.y = (_Float16)0.0f;
        #pragma unroll
        for (int g = 0; g < 64; g++) {
            acc2 += s_W[g0 + g][fp] * s_hd[a][g0 + g];
        }
        s_red[ks2][a][2 * fp]     = (float)acc2.x;
        s_red[ks2][a][2 * fp + 1] = (float)acc2.y;
    }
    __syncthreads();
    {
        int f = tid & 127, aa = tid >> 7;
        int iaa = (n0 + aa >= n1) ? 1 : 0;
        s_h1[aa][f] = fast_tanh(s_red[0][aa][f] + s_red[1][aa][f] + b1[iaa * 128 + f]);
    }
    __syncthreads();

    // ---- layer 2 + energy reduction ----
    {
        int f = tid & 127, aa = tid >> 7;
        int iaa = (n0 + aa >= n1) ? 1 : 0;
        float pv = s_h1[aa][f] * W2[iaa * 128 + f];
        #pragma unroll
        for (int m = 1; m < 64; m <<= 1) pv += __shfl_xor(pv, m);
        if ((tid & 63) == 0) s_part[tid >> 6] = pv;   // wave w: atom w>>1
    }
    __syncthreads();
    if (tid == 0) {
        float e = 0.0f;
        #pragma unroll
        for (int w = 0; w < 4; w++) {
            int iaa = (n0 + w >= n1) ? 1 : 0;
            e += s_part[2 * w] + s_part[2 * w + 1] + b2[iaa] + Ebias[iaa];
        }
        atomicAdd(out, e);
    }
}

extern "C" void kernel_launch(void* const* d_in, const int* in_sizes, int n_in,
                              void* d_out, int out_size, void* d_ws, size_t ws_size,
                              hipStream_t stream) {
    const float* coord   = (const float*)d_in[0];
    const float* box     = (const float*)d_in[1];
    const float* srmean  = (const float*)d_in[2];
    const float* srstd   = (const float*)d_in[3];
    const float* xrsrstd = (const float*)d_in[4];
    const float* Gbias   = (const float*)d_in[5];
    const float* Ebias   = (const float*)d_in[6];
    const float* eW0     = (const float*)d_in[7];
    const float* eb0     = (const float*)d_in[8];
    const float* eW1     = (const float*)d_in[9];
    const float* eb1     = (const float*)d_in[10];
    const float* eW2     = (const float*)d_in[11];
    const float* eb2     = (const float*)d_in[12];
    const float* fW0     = (const float*)d_in[13];
    const float* fb0     = (const float*)d_in[14];
    const float* fW1     = (const float*)d_in[15];
    const float* fb1     = (const float*)d_in[16];
    const float* fW2     = (const float*)d_in[17];
    const float* fb2     = (const float*)d_in[18];
    const int*   n1p     = (const int*)d_in[19];

    const int N = in_sizes[0] / 3;          // 1024
    h2* featbuf = (h2*)d_ws;                // N*512 h2 = 2 MB

    (void)hipMemsetAsync(d_out, 0, sizeof(float), stream);
    k_embed<<<N, 256, 0, stream>>>(coord, box, srmean, srstd, xrsrstd, Gbias,
                                   eW0, eb0, eW1, eb1, eW2, eb2, n1p, featbuf, N);
    k_fit<<<N / 4, 512, 0, stream>>>(featbuf, fW0, fb0, fW1, fb1, fW2, fb2,
                                     Ebias, n1p, (float*)d_out);
}

// Round 6
// 54.021 us; speedup vs baseline: 1.4657x; 1.1770x over previous
//
#include <hip/hip_runtime.h>

#define RCUT 6.0f

typedef _Float16 h2 __attribute__((ext_vector_type(2)));
typedef _Float16 h8 __attribute__((ext_vector_type(8)));
typedef float    f4 __attribute__((ext_vector_type(4)));

__device__ __forceinline__ float fast_tanh(float x) {
    float e = __expf(2.0f * x);              // inf for large x -> tanh=1
    return 1.0f - 2.0f * __builtin_amdgcn_rcpf(e + 1.0f);
}

#if __has_builtin(__builtin_amdgcn_fdot2)
__device__ __forceinline__ float dot2(h2 a, h2 b, float c) {
    return __builtin_amdgcn_fdot2(a, b, c, false);
}
#else
__device__ __forceinline__ float dot2(h2 a, h2 b, float c) {
    return (float)a.x * (float)b.x + (float)a.y * (float)b.y + c;
}
#endif

__device__ __forceinline__ h2 pkh(float a, float b) {
#if __has_builtin(__builtin_amdgcn_cvt_pkrtz)
    union { __fp16 __attribute__((ext_vector_type(2))) r; h2 h; } u;
    u.r = __builtin_amdgcn_cvt_pkrtz(a, b);
    return u.h;
#else
    h2 r; r.x = (_Float16)a; r.y = (_Float16)b; return r;
#endif
}

// ---------------- Kernel 1: neighbor scan + embed MLP (W2/stage2 via MFMA) ---
__global__ __launch_bounds__(256, 4) void k_embed(
    const float* __restrict__ coord, const float* __restrict__ box,
    const float* __restrict__ srmean, const float* __restrict__ srstd,
    const float* __restrict__ xrsrstd, const float* __restrict__ Gbias,
    const float* __restrict__ eW0, const float* __restrict__ eb0,
    const float* __restrict__ eW1, const float* __restrict__ eb1,
    const float* __restrict__ eW2, const float* __restrict__ eb2,
    const int* __restrict__ n1p, h2* __restrict__ feat, int N)
{
    const int n   = blockIdx.x;
    const int tid = threadIdx.x;
    const int n1  = *n1p;
    const int ti  = (n >= n1) ? 1 : 0;

    __shared__ struct {
        float    w0[2][16], b0[2][16];
        _Float16 w1t[2][32][16];       // [j][g][f]
        float    b1[2][32];
    } sw;
    __shared__ _Float16 s_h1[128][40];   // h1 rows (32 f16 + pad to 80B, 16B-aligned chunks)
    __shared__ _Float16 s_ef[4][4][64][8]; // e in B-frag layout [nt][ks][slot][j]
    __shared__ float s_coef[4][128];     // srbias, Rx, Ry, Rz per pair
    __shared__ unsigned short s_nbr[512];
    __shared__ float s_g4[256];          // G[4][64]
    __shared__ int   s_wcnt[4], s_wcnt0[4];

    // ---- weight staging (W0/W1 only; W2 goes straight to registers) ----
    for (int t = tid; t < 32; t += 256) { int j = t >> 4, f = t & 15;
        sw.w0[j][f] = eW0[(2 * ti + j) * 16 + f];
        sw.b0[j][f] = eb0[(2 * ti + j) * 16 + f]; }
    for (int t = tid; t < 1024; t += 256) { int j = t >> 9, r = t & 511, f = r >> 5, g = r & 31;
        sw.w1t[j][g][f] = (_Float16)eW1[(2 * ti + j) * 512 + f * 32 + g]; }
    for (int t = tid; t < 64; t += 256) { int j = t >> 5, g = t & 31;
        sw.b1[j][g] = eb1[(2 * ti + j) * 32 + g]; }

    const int wid = tid >> 6, lane = tid & 63;
    const int l15 = lane & 15, lk = lane >> 4;

    // ---- W2 B-fragments + b2 into registers (L2-hot, once per block) ----
    // B[k][c] frag: lane holds c = 16*nt + l15, k = 8*lk + r
    h8 bf[2][4];
    float b2r[2][4];
    #pragma unroll
    for (int j = 0; j < 2; j++) {
        const float* w2g = eW2 + (size_t)(2 * ti + j) * 2048;
        #pragma unroll
        for (int nt = 0; nt < 4; nt++) {
            h8 v;
            #pragma unroll
            for (int r = 0; r < 8; r++)
                v[r] = (_Float16)w2g[(8 * lk + r) * 64 + nt * 16 + l15];
            bf[j][nt] = v;
            b2r[j][nt] = eb2[(2 * ti + j) * 64 + nt * 16 + l15];
        }
    }

    const float Lx = box[0], Ly = box[4], Lz = box[8];
    const float iLx = 1.0f / Lx, iLy = 1.0f / Ly, iLz = 1.0f / Lz;
    const float xn = coord[n], yn = coord[N + n], zn = coord[2 * N + n];

    // ---- parallel deterministic neighbor scan (m ascending => type-sorted) --
    {
        unsigned long long bal[4];
        int wtotal = 0, wtotal0 = 0;
        const int mystart = wid * 256;
        #pragma unroll
        for (int r = 0; r < 4; r++) {
            int m = mystart + r * 64 + lane;
            float dx = coord[m] - xn;         dx -= Lx * rintf(dx * iLx);
            float dy = coord[N + m] - yn;     dy -= Ly * rintf(dy * iLy);
            float dz = coord[2 * N + m] - zn; dz -= Lz * rintf(dz * iLz);
            float r2 = dx * dx + dy * dy + dz * dz;
            bool pred = (r2 < RCUT * RCUT) && (m != n);
            bal[r] = __ballot(pred);
            unsigned long long bal0 = __ballot(pred && (m < n1));
            wtotal  += (int)__popcll(bal[r]);
            wtotal0 += (int)__popcll(bal0);
        }
        if (lane == 0) { s_wcnt[wid] = wtotal; s_wcnt0[wid] = wtotal0; }
        __syncthreads();
        int base = 0;
        for (int w = 0; w < wid; w++) base += s_wcnt[w];
        #pragma unroll
        for (int r = 0; r < 4; r++) {
            bool pred = (bal[r] >> lane) & 1ull;
            int pos = (int)__popcll(bal[r] & ((1ull << lane) - 1ull));
            if (pred && (base + pos) < 512)
                s_nbr[base + pos] = (unsigned short)(wid * 256 + r * 64 + lane);
            base += (int)__popcll(bal[r]);
        }
    }
    __syncthreads();
    int cnt  = s_wcnt[0] + s_wcnt[1] + s_wcnt[2] + s_wcnt[3];
    int cnt0 = s_wcnt0[0] + s_wcnt0[1] + s_wcnt0[2] + s_wcnt0[3];
    if (cnt > 512) cnt = 512;

    const float srm  = srmean[ti];
    const float isrs = 1.0f / srstd[ti];
    const float ixrs = 1.0f / xrsrstd[ti];

    const int p  = tid & 127;   // stage-1 pair slot
    const int hh = tid >> 7;    // stage-1 g-half (W1 outputs 16*hh..16*hh+15)
    const int dummy = (n + 1 < N) ? (n + 1) : 0;

    f4 gacc = {0.0f, 0.0f, 0.0f, 0.0f};
    const f4 zf4 = {0.0f, 0.0f, 0.0f, 0.0f};

    const int ntiles = (cnt + 127) >> 7;
    for (int t = 0; t < ntiles; t++) {
        __syncthreads();   // B1: protect s_coef/s_h1/s_ef from previous readers
        {   // ---- stage 1: per-pair W0+W1 (g-half) -> s_h1, coeffs -> s_coef
            const int pi = (t << 7) + p;
            const bool valid = pi < cnt;
            int m = valid ? (int)s_nbr[pi] : dummy;
            float dx = coord[m] - xn;         dx -= Lx * rintf(dx * iLx);
            float dy = coord[N + m] - yn;     dy -= Ly * rintf(dy * iLy);
            float dz = coord[2 * N + m] - zn; dz -= Lz * rintf(dz * iLz);
            float r2 = dx * dx + dy * dy + dz * dz;
            float r  = sqrtf(r2);
            float rinv = __builtin_amdgcn_rcpf(r);
            float u  = r * (1.0f / RCUT);
            float u3 = u * u * u;
            float sw_ = ((-6.0f * u + 15.0f) * u - 10.0f) * u3 + 1.0f;
            if (!valid) sw_ = 0.0f;
            float sr  = sw_ * rinv;
            float srn = (sr - srm) * isrs;
            if (hh == 0) {
                float csr = valid ? sr * isrs : 0.0f;
                float crs = valid ? (sr * rinv * ixrs + 1e-15f) : 0.0f;
                s_coef[0][p] = csr;
                s_coef[1][p] = crs * dx;
                s_coef[2][p] = crs * dy;
                s_coef[3][p] = crs * dz;
            }

            const int j = (m >= n1) ? 1 : 0;
            // W0: 1 -> 16
            float h0[16];
            #pragma unroll
            for (int f = 0; f < 16; f++)
                h0[f] = fast_tanh(fmaf(srn, sw.w0[j][f], sw.b0[j][f]));
            h2 h0p[8];
            #pragma unroll
            for (int q = 0; q < 8; q++) h0p[q] = pkh(h0[2 * q], h0[2 * q + 1]);

            // W1: my 16 of 32 outputs (dot2)
            #pragma unroll
            for (int q = 0; q < 8; q++) {
                float hv[2];
                #pragma unroll
                for (int u_ = 0; u_ < 2; u_++) {
                    int g = 16 * hh + 2 * q + u_;
                    union { float4 f4v; h2 h[4]; } wa, wb;
                    wa.f4v = *(const float4*)&sw.w1t[j][g][0];
                    wb.f4v = *(const float4*)&sw.w1t[j][g][8];
                    float a = sw.b1[j][g];
                    #pragma unroll
                    for (int qq = 0; qq < 4; qq++) a = dot2(h0p[qq], wa.h[qq], a);
                    #pragma unroll
                    for (int qq = 0; qq < 4; qq++) a = dot2(h0p[4 + qq], wb.h[qq], a);
                    hv[u_] = fast_tanh(a);
                }
                *(h2*)&s_h1[p][16 * hh + 2 * q] = pkh(hv[0], hv[1]);
            }
        }
        __syncthreads();   // B2: s_h1 + s_coef ready

        // ---- W2 via MFMA: e[128][64] = tanh(h1[128][32] @ W2[32][64] + b2)
        {
            const int t128 = t << 7;
            #pragma unroll
            for (int mt2 = 0; mt2 < 2; mt2++) {
                const int mt  = 2 * wid + mt2;
                const int row = 16 * mt + l15;
                h8 a = *(const h8*)&s_h1[row][8 * lk];
                const int gpb = 16 * mt;
                const bool need0 = (t128 + gpb) < cnt0;
                const bool need1 = (t128 + gpb + 15) >= cnt0;
                #pragma unroll
                for (int nt = 0; nt < 4; nt++) {
                    f4 d0 = zf4, d1 = zf4;
                    if (need0) d0 = __builtin_amdgcn_mfma_f32_16x16x32_f16(a, bf[0][nt], zf4, 0, 0, 0);
                    if (need1) d1 = __builtin_amdgcn_mfma_f32_16x16x32_f16(a, bf[1][nt], zf4, 0, 0, 0);
                    #pragma unroll
                    for (int r = 0; r < 4; r++) {
                        int gp = gpb + 4 * lk + r;        // pair index within tile
                        bool is0 = (t128 + gp) < cnt0;
                        float dv = is0 ? d0[r] : d1[r];
                        float ev = fast_tanh(dv + (is0 ? b2r[0][nt] : b2r[1][nt]));
                        s_ef[nt][gp >> 5][l15 + 16 * ((gp & 31) >> 3)][gp & 7] = (_Float16)ev;
                    }
                }
            }
        }
        __syncthreads();   // B3: s_ef ready

        // ---- stage 2 via MFMA: G[4pad16][64] += coef[4][128] @ e[128][64]
        {
            #pragma unroll
            for (int ks = 0; ks < 4; ks++) {
                h8 ac;
                #pragma unroll
                for (int r = 0; r < 8; r++) {
                    int kk = 32 * ks + 8 * lk + r;
                    float cv = (l15 < 4) ? s_coef[l15][kk] : 0.0f;
                    ac[r] = (_Float16)cv;
                }
                h8 eb = *(const h8*)&s_ef[wid][ks][lane][0];
                gacc = __builtin_amdgcn_mfma_f32_16x16x32_f16(ac, eb, gacc, 0, 0, 0);
            }
        }
    }

    // ---- epilogue: G rows live in lanes 0..15 (lk==0), regs r=k ----
    if (lane < 16) {
        #pragma unroll
        for (int r = 0; r < 4; r++) {
            float gv = gacc[r] * (1.0f / 64.0f);
            if (r == 0) gv += Gbias[16 * wid + lane];
            s_g4[r * 64 + 16 * wid + lane] = gv;
        }
    }
    __syncthreads();
    {
        h2* outp = feat + (size_t)n * 512;
        #pragma unroll
        for (int q = 0; q < 2; q++) {
            int o2 = tid + 256 * q;          // h2 index; elements 2*o2, 2*o2+1
            int a = o2 >> 5;
            int c = (2 * o2) & 63;
            float ga0 = s_g4[a],       ga1 = s_g4[64 + a];
            float ga2 = s_g4[128 + a], ga3 = s_g4[192 + a];
            float s0 = ga0 * s_g4[c];
            s0 = fmaf(ga1, s_g4[64 + c],  s0);
            s0 = fmaf(ga2, s_g4[128 + c], s0);
            s0 = fmaf(ga3, s_g4[192 + c], s0);
            float s1 = ga0 * s_g4[c + 1];
            s1 = fmaf(ga1, s_g4[64 + c + 1],  s1);
            s1 = fmaf(ga2, s_g4[128 + c + 1], s1);
            s1 = fmaf(ga3, s_g4[192 + c + 1], s1);
            outp[o2] = pkh(s0, s1);
        }
    }
}

// ---------------- Kernel 2: fit net, LDS-tiled fp16 GEMM (4 atoms / block) ---
__global__ __launch_bounds__(512) void k_fit(
    const h2* __restrict__ feat,
    const float* __restrict__ W0, const float* __restrict__ b0,
    const float* __restrict__ W1, const float* __restrict__ b1,
    const float* __restrict__ W2, const float* __restrict__ b2,
    const float* __restrict__ Ebias, const int* __restrict__ n1p,
    float* __restrict__ out)
{
    __shared__ h2    s_W[128][64];     // weight tile fp16: [row][col-pair] (32 KB)
    __shared__ h2    s_fd[4][1024];    // feat, duplicated lanes (16 KB)
    __shared__ float s_red[2][4][128];
    __shared__ h2    s_hd[4][128];
    __shared__ float s_h1[4][128];
    __shared__ float s_part[8];

    const int tid = threadIdx.x;
    const int n0  = blockIdx.x * 4;
    const int n1  = *n1p;
    const int ia  = (n0 >= n1) ? 1 : 0;

    const int fp  = tid & 63;
    const int ks2 = (tid >> 6) & 1;
    const int a   = tid >> 7;

    {
        const unsigned int* src = (const unsigned int*)(feat + (size_t)n0 * 512);
        #pragma unroll
        for (int q = 0; q < 4; q++) {
            int idx = tid + 512 * q;
            union { unsigned int u; h2 h; } cv; cv.u = src[idx];
            int aa = idx >> 9, xp = idx & 511;
            h2 lo; lo.x = cv.h.x; lo.y = cv.h.x;
            h2 hi; hi.x = cv.h.y; hi.y = cv.h.y;
            s_fd[aa][2 * xp]     = lo;
            s_fd[aa][2 * xp + 1] = hi;
        }
    }

    // ---- layer 0: 1024 -> 128 over 8 LDS tiles (4 independent fp16 chains) --
    const float2* wsrc = (const float2*)(W0 + (size_t)ia * 131072);
    float2 pre[16];
    #pragma unroll
    for (int q = 0; q < 16; q++) pre[q] = wsrc[tid + 512 * q];

    float af0 = 0.0f, af1 = 0.0f;
    for (int kt = 0; kt < 8; kt++) {
        __syncthreads();
        #pragma unroll
        for (int q = 0; q < 16; q++) {
            int i = tid + 512 * q;
            ((h2*)s_W)[i] = pkh(pre[q].x, pre[q].y);
        }
        if (kt < 7) {
            #pragma unroll
            for (int q = 0; q < 16; q++) pre[q] = wsrc[(kt + 1) * 8192 + tid + 512 * q];
        }
        __syncthreads();
        const int x0 = ks2 * 64, xg = kt * 128 + x0;
        h2 ac0 = {}, ac1 = {}, ac2 = {}, ac3 = {};
        #pragma unroll
        for (int xx = 0; xx < 64; xx += 4) {
            ac0 += s_W[x0 + xx + 0][fp] * s_fd[a][xg + xx + 0];
            ac1 += s_W[x0 + xx + 1][fp] * s_fd[a][xg + xx + 1];
            ac2 += s_W[x0 + xx + 2][fp] * s_fd[a][xg + xx + 2];
            ac3 += s_W[x0 + xx + 3][fp] * s_fd[a][xg + xx + 3];
        }
        h2 s = (ac0 + ac1) + (ac2 + ac3);
        af0 += (float)s.x;
        af1 += (float)s.y;
    }
    s_red[ks2][a][2 * fp]     = af0;
    s_red[ks2][a][2 * fp + 1] = af1;
    __syncthreads();
    {
        int f = tid & 127, aa = tid >> 7;
        int iaa = (n0 + aa >= n1) ? 1 : 0;
        float h = fast_tanh(s_red[0][aa][f] + s_red[1][aa][f] + b0[iaa * 128 + f]);
        h2 d; d.x = (_Float16)h; d.y = d.x;
        s_hd[aa][f] = d;
    }
    __syncthreads();

    // ---- layer 1: 128 -> 128 ----
    {
        const float2* w1src = (const float2*)(W1 + (size_t)ia * 16384);
        float2 p1[16];
        #pragma unroll
        for (int q = 0; q < 16; q++) p1[q] = w1src[tid + 512 * q];
        #pragma unroll
        for (int q = 0; q < 16; q++) {
            int i = tid + 512 * q;
            ((h2*)s_W)[i] = pkh(p1[q].x, p1[q].y);
        }
    }
    __syncthreads();
    {
        const int g0 = ks2 * 64;
        h2 ac0 = {}, ac1 = {}, ac2 = {}, ac3 = {};
        #pragma unroll
        for (int g = 0; g < 64; g += 4) {
            ac0 += s_W[g0 + g + 0][fp] * s_hd[a][g0 + g + 0];
            ac1 += s_W[g0 + g + 1][fp] * s_hd[a][g0 + g + 1];
            ac2 += s_W[g0 + g + 2][fp] * s_hd[a][g0 + g + 2];
            ac3 += s_W[g0 + g + 3][fp] * s_hd[a][g0 + g + 3];
        }
        h2 s = (ac0 + ac1) + (ac2 + ac3);
        s_red[ks2][a][2 * fp]     = (float)s.x;
        s_red[ks2][a][2 * fp + 1] = (float)s.y;
    }
    __syncthreads();
    {
        int f = tid & 127, aa = tid >> 7;
        int iaa = (n0 + aa >= n1) ? 1 : 0;
        s_h1[aa][f] = fast_tanh(s_red[0][aa][f] + s_red[1][aa][f] + b1[iaa * 128 + f]);
    }
    __syncthreads();

    // ---- layer 2 + energy reduction ----
    {
        int f = tid & 127, aa = tid >> 7;
        int iaa = (n0 + aa >= n1) ? 1 : 0;
        float pv = s_h1[aa][f] * W2[iaa * 128 + f];
        #pragma unroll
        for (int m = 1; m < 64; m <<= 1) pv += __shfl_xor(pv, m);
        if ((tid & 63) == 0) s_part[tid >> 6] = pv;
    }
    __syncthreads();
    if (tid == 0) {
        float e = 0.0f;
        #pragma unroll
        for (int w = 0; w < 4; w++) {
            int iaa = (n0 + w >= n1) ? 1 : 0;
            e += s_part[2 * w] + s_part[2 * w + 1] + b2[iaa] + Ebias[iaa];
        }
        atomicAdd(out, e);
    }
}

extern "C" void kernel_launch(void* const* d_in, const int* in_sizes, int n_in,
                              void* d_out, int out_size, void* d_ws, size_t ws_size,
                              hipStream_t stream) {
    const float* coord   = (const float*)d_in[0];
    const float* box     = (const float*)d_in[1];
    const float* srmean  = (const float*)d_in[2];
    const float* srstd   = (const float*)d_in[3];
    const float* xrsrstd = (const float*)d_in[4];
    const float* Gbias   = (const float*)d_in[5];
    const float* Ebias   = (const float*)d_in[6];
    const float* eW0     = (const float*)d_in[7];
    const float* eb0     = (const float*)d_in[8];
    const float* eW1     = (const float*)d_in[9];
    const float* eb1     = (const float*)d_in[10];
    const float* eW2     = (const float*)d_in[11];
    const float* eb2     = (const float*)d_in[12];
    const float* fW0     = (const float*)d_in[13];
    const float* fb0     = (const float*)d_in[14];
    const float* fW1     = (const float*)d_in[15];
    const float* fb1     = (const float*)d_in[16];
    const float* fW2     = (const float*)d_in[17];
    const float* fb2     = (const float*)d_in[18];
    const int*   n1p     = (const int*)d_in[19];

    const int N = in_sizes[0] / 3;          // 1024
    h2* featbuf = (h2*)d_ws;                // N*512 h2 = 2 MB

    (void)hipMemsetAsync(d_out, 0, sizeof(float), stream);
    k_embed<<<N, 256, 0, stream>>>(coord, box, srmean, srstd, xrsrstd, Gbias,
                                   eW0, eb0, eW1, eb1, eW2, eb2, n1p, featbuf, N);
    k_fit<<<N / 4, 512, 0, stream>>>(featbuf, fW0, fb0, fW1, fb1, fW2, fb2,
                                     Ebias, n1p, (float*)d_out);
}

// Round 7
// 47.873 us; speedup vs baseline: 1.6540x; 1.1284x over previous
//
#include <hip/hip_runtime.h>

#define RCUT 6.0f

typedef _Float16 h2 __attribute__((ext_vector_type(2)));
typedef _Float16 h8 __attribute__((ext_vector_type(8)));
typedef float    f4 __attribute__((ext_vector_type(4)));

__device__ __forceinline__ float fast_tanh(float x) {
    float e = __expf(2.0f * x);              // inf for large x -> tanh=1
    return 1.0f - 2.0f * __builtin_amdgcn_rcpf(e + 1.0f);
}

#if __has_builtin(__builtin_amdgcn_fdot2)
__device__ __forceinline__ float dot2(h2 a, h2 b, float c) {
    return __builtin_amdgcn_fdot2(a, b, c, false);
}
#else
__device__ __forceinline__ float dot2(h2 a, h2 b, float c) {
    return (float)a.x * (float)b.x + (float)a.y * (float)b.y + c;
}
#endif

__device__ __forceinline__ h2 pkh(float a, float b) {
#if __has_builtin(__builtin_amdgcn_cvt_pkrtz)
    union { __fp16 __attribute__((ext_vector_type(2))) r; h2 h; } u;
    u.r = __builtin_amdgcn_cvt_pkrtz(a, b);
    return u.h;
#else
    h2 r; r.x = (_Float16)a; r.y = (_Float16)b; return r;
#endif
}

// ---------------- Kernel 1: neighbor scan + embed MLP (W2/stage2 via MFMA) ---
__global__ __launch_bounds__(256, 4) void k_embed(
    const float* __restrict__ coord, const float* __restrict__ box,
    const float* __restrict__ srmean, const float* __restrict__ srstd,
    const float* __restrict__ xrsrstd, const float* __restrict__ Gbias,
    const float* __restrict__ eW0, const float* __restrict__ eb0,
    const float* __restrict__ eW1, const float* __restrict__ eb1,
    const float* __restrict__ eW2, const float* __restrict__ eb2,
    const int* __restrict__ n1p, h2* __restrict__ feat, int N)
{
    const int n   = blockIdx.x;
    const int tid = threadIdx.x;
    const int n1  = *n1p;
    const int ti  = (n >= n1) ? 1 : 0;

    __shared__ struct {
        float    w0[2][16], b0[2][16];
        _Float16 w1t[2][32][16];       // [j][g][f]
        float    b1[2][32];
    } sw;
    __shared__ _Float16 s_h1[128][40];   // h1 rows (32 f16 + pad to 80B, 16B-aligned chunks)
    __shared__ _Float16 s_ef[4][4][64][8]; // e in B-frag layout [nt][ks][slot][j]
    __shared__ float s_coef[4][128];     // srbias, Rx, Ry, Rz per pair
    __shared__ unsigned short s_nbr[512];
    __shared__ float s_g4[256];          // G[4][64]
    __shared__ int   s_wcnt[4], s_wcnt0[4];

    // ---- weight staging (W0/W1 only; W2 goes straight to registers) ----
    for (int t = tid; t < 32; t += 256) { int j = t >> 4, f = t & 15;
        sw.w0[j][f] = eW0[(2 * ti + j) * 16 + f];
        sw.b0[j][f] = eb0[(2 * ti + j) * 16 + f]; }
    for (int t = tid; t < 1024; t += 256) { int j = t >> 9, r = t & 511, f = r >> 5, g = r & 31;
        sw.w1t[j][g][f] = (_Float16)eW1[(2 * ti + j) * 512 + f * 32 + g]; }
    for (int t = tid; t < 64; t += 256) { int j = t >> 5, g = t & 31;
        sw.b1[j][g] = eb1[(2 * ti + j) * 32 + g]; }

    const int wid = tid >> 6, lane = tid & 63;
    const int l15 = lane & 15, lk = lane >> 4;

    // ---- W2 B-fragments + b2 into registers (L2-hot, once per block) ----
    h8 bf[2][4];
    float b2r[2][4];
    #pragma unroll
    for (int j = 0; j < 2; j++) {
        const float* w2g = eW2 + (size_t)(2 * ti + j) * 2048;
        #pragma unroll
        for (int nt = 0; nt < 4; nt++) {
            h8 v;
            #pragma unroll
            for (int r = 0; r < 8; r++)
                v[r] = (_Float16)w2g[(8 * lk + r) * 64 + nt * 16 + l15];
            bf[j][nt] = v;
            b2r[j][nt] = eb2[(2 * ti + j) * 64 + nt * 16 + l15];
        }
    }

    const float Lx = box[0], Ly = box[4], Lz = box[8];
    const float iLx = 1.0f / Lx, iLy = 1.0f / Ly, iLz = 1.0f / Lz;
    const float xn = coord[n], yn = coord[N + n], zn = coord[2 * N + n];

    // ---- parallel deterministic neighbor scan (m ascending => type-sorted) --
    {
        unsigned long long bal[4];
        int wtotal = 0, wtotal0 = 0;
        const int mystart = wid * 256;
        #pragma unroll
        for (int r = 0; r < 4; r++) {
            int m = mystart + r * 64 + lane;
            float dx = coord[m] - xn;         dx -= Lx * rintf(dx * iLx);
            float dy = coord[N + m] - yn;     dy -= Ly * rintf(dy * iLy);
            float dz = coord[2 * N + m] - zn; dz -= Lz * rintf(dz * iLz);
            float r2 = dx * dx + dy * dy + dz * dz;
            bool pred = (r2 < RCUT * RCUT) && (m != n);
            bal[r] = __ballot(pred);
            unsigned long long bal0 = __ballot(pred && (m < n1));
            wtotal  += (int)__popcll(bal[r]);
            wtotal0 += (int)__popcll(bal0);
        }
        if (lane == 0) { s_wcnt[wid] = wtotal; s_wcnt0[wid] = wtotal0; }
        __syncthreads();
        int base = 0;
        for (int w = 0; w < wid; w++) base += s_wcnt[w];
        #pragma unroll
        for (int r = 0; r < 4; r++) {
            bool pred = (bal[r] >> lane) & 1ull;
            int pos = (int)__popcll(bal[r] & ((1ull << lane) - 1ull));
            if (pred && (base + pos) < 512)
                s_nbr[base + pos] = (unsigned short)(wid * 256 + r * 64 + lane);
            base += (int)__popcll(bal[r]);
        }
    }
    __syncthreads();
    int cnt  = s_wcnt[0] + s_wcnt[1] + s_wcnt[2] + s_wcnt[3];
    int cnt0 = s_wcnt0[0] + s_wcnt0[1] + s_wcnt0[2] + s_wcnt0[3];
    if (cnt > 512) cnt = 512;

    const float srm  = srmean[ti];
    const float isrs = 1.0f / srstd[ti];
    const float ixrs = 1.0f / xrsrstd[ti];

    const int p  = tid & 127;   // stage-1 pair slot
    const int hh = tid >> 7;    // stage-1 g-half (W1 outputs 16*hh..16*hh+15)
    const int dummy = (n + 1 < N) ? (n + 1) : 0;

    f4 gacc = {0.0f, 0.0f, 0.0f, 0.0f};
    const f4 zf4 = {0.0f, 0.0f, 0.0f, 0.0f};

    const int ntiles = (cnt + 127) >> 7;
    for (int t = 0; t < ntiles; t++) {
        __syncthreads();   // B1: protect s_coef/s_h1/s_ef from previous readers
        {   // ---- stage 1: per-pair W0+W1 (g-half) -> s_h1, coeffs -> s_coef
            const int pi = (t << 7) + p;
            const bool valid = pi < cnt;
            int m = valid ? (int)s_nbr[pi] : dummy;
            float dx = coord[m] - xn;         dx -= Lx * rintf(dx * iLx);
            float dy = coord[N + m] - yn;     dy -= Ly * rintf(dy * iLy);
            float dz = coord[2 * N + m] - zn; dz -= Lz * rintf(dz * iLz);
            float r2 = dx * dx + dy * dy + dz * dz;
            float r  = sqrtf(r2);
            float rinv = __builtin_amdgcn_rcpf(r);
            float u  = r * (1.0f / RCUT);
            float u3 = u * u * u;
            float sw_ = ((-6.0f * u + 15.0f) * u - 10.0f) * u3 + 1.0f;
            if (!valid) sw_ = 0.0f;
            float sr  = sw_ * rinv;
            float srn = (sr - srm) * isrs;
            if (hh == 0) {
                float csr = valid ? sr * isrs : 0.0f;
                float crs = valid ? (sr * rinv * ixrs + 1e-15f) : 0.0f;
                s_coef[0][p] = csr;
                s_coef[1][p] = crs * dx;
                s_coef[2][p] = crs * dy;
                s_coef[3][p] = crs * dz;
            }

            const int j = (m >= n1) ? 1 : 0;
            // W0: 1 -> 16
            float h0[16];
            #pragma unroll
            for (int f = 0; f < 16; f++)
                h0[f] = fast_tanh(fmaf(srn, sw.w0[j][f], sw.b0[j][f]));
            h2 h0p[8];
            #pragma unroll
            for (int q = 0; q < 8; q++) h0p[q] = pkh(h0[2 * q], h0[2 * q + 1]);

            // W1: my 16 of 32 outputs (dot2)
            #pragma unroll
            for (int q = 0; q < 8; q++) {
                float hv[2];
                #pragma unroll
                for (int u_ = 0; u_ < 2; u_++) {
                    int g = 16 * hh + 2 * q + u_;
                    union { float4 f4v; h2 h[4]; } wa, wb;
                    wa.f4v = *(const float4*)&sw.w1t[j][g][0];
                    wb.f4v = *(const float4*)&sw.w1t[j][g][8];
                    float a = sw.b1[j][g];
                    #pragma unroll
                    for (int qq = 0; qq < 4; qq++) a = dot2(h0p[qq], wa.h[qq], a);
                    #pragma unroll
                    for (int qq = 0; qq < 4; qq++) a = dot2(h0p[4 + qq], wb.h[qq], a);
                    hv[u_] = fast_tanh(a);
                }
                *(h2*)&s_h1[p][16 * hh + 2 * q] = pkh(hv[0], hv[1]);
            }
        }
        __syncthreads();   // B2: s_h1 + s_coef ready

        // ---- W2 via MFMA: e[128][64] = tanh(h1[128][32] @ W2[32][64] + b2)
        {
            const int t128 = t << 7;
            #pragma unroll
            for (int mt2 = 0; mt2 < 2; mt2++) {
                const int mt  = 2 * wid + mt2;
                const int row = 16 * mt + l15;
                h8 a = *(const h8*)&s_h1[row][8 * lk];
                const int gpb = 16 * mt;
                const bool need0 = (t128 + gpb) < cnt0;
                const bool need1 = (t128 + gpb + 15) >= cnt0;
                #pragma unroll
                for (int nt = 0; nt < 4; nt++) {
                    f4 d0 = zf4, d1 = zf4;
                    if (need0) d0 = __builtin_amdgcn_mfma_f32_16x16x32_f16(a, bf[0][nt], zf4, 0, 0, 0);
                    if (need1) d1 = __builtin_amdgcn_mfma_f32_16x16x32_f16(a, bf[1][nt], zf4, 0, 0, 0);
                    #pragma unroll
                    for (int r = 0; r < 4; r++) {
                        int gp = gpb + 4 * lk + r;        // pair index within tile
                        bool is0 = (t128 + gp) < cnt0;
                        float dv = is0 ? d0[r] : d1[r];
                        float ev = fast_tanh(dv + (is0 ? b2r[0][nt] : b2r[1][nt]));
                        s_ef[nt][gp >> 5][l15 + 16 * ((gp & 31) >> 3)][gp & 7] = (_Float16)ev;
                    }
                }
            }
        }
        __syncthreads();   // B3: s_ef ready

        // ---- stage 2 via MFMA: G[4pad16][64] += coef[4][128] @ e[128][64]
        {
            #pragma unroll
            for (int ks = 0; ks < 4; ks++) {
                h8 ac;
                #pragma unroll
                for (int r = 0; r < 8; r++) {
                    int kk = 32 * ks + 8 * lk + r;
                    float cv = (l15 < 4) ? s_coef[l15][kk] : 0.0f;
                    ac[r] = (_Float16)cv;
                }
                h8 eb = *(const h8*)&s_ef[wid][ks][lane][0];
                gacc = __builtin_amdgcn_mfma_f32_16x16x32_f16(ac, eb, gacc, 0, 0, 0);
            }
        }
    }

    // ---- epilogue: G rows live in lanes 0..15 (lk==0), regs r=k ----
    if (lane < 16) {
        #pragma unroll
        for (int r = 0; r < 4; r++) {
            float gv = gacc[r] * (1.0f / 64.0f);
            if (r == 0) gv += Gbias[16 * wid + lane];
            s_g4[r * 64 + 16 * wid + lane] = gv;
        }
    }
    __syncthreads();
    {
        h2* outp = feat + (size_t)n * 512;
        #pragma unroll
        for (int q = 0; q < 2; q++) {
            int o2 = tid + 256 * q;          // h2 index; elements 2*o2, 2*o2+1
            int a = o2 >> 5;
            int c = (2 * o2) & 63;
            float ga0 = s_g4[a],       ga1 = s_g4[64 + a];
            float ga2 = s_g4[128 + a], ga3 = s_g4[192 + a];
            float s0 = ga0 * s_g4[c];
            s0 = fmaf(ga1, s_g4[64 + c],  s0);
            s0 = fmaf(ga2, s_g4[128 + c], s0);
            s0 = fmaf(ga3, s_g4[192 + c], s0);
            float s1 = ga0 * s_g4[c + 1];
            s1 = fmaf(ga1, s_g4[64 + c + 1],  s1);
            s1 = fmaf(ga2, s_g4[128 + c + 1], s1);
            s1 = fmaf(ga3, s_g4[192 + c + 1], s1);
            outp[o2] = pkh(s0, s1);
        }
    }
}

// ---------------- Kernel 1.5: transpose + fp16-convert fit weights ----------
// fW0 [2][1024][128] f32 -> W0ht [2][128][1024] f16; fW1 [2][128][128] likewise.
__global__ __launch_bounds__(256) void k_prep(
    const float* __restrict__ fW0, const float* __restrict__ fW1,
    _Float16* __restrict__ W0ht, _Float16* __restrict__ W1ht)
{
    __shared__ float s_t[32][33];
    const int b = blockIdx.x;
    const int tid = threadIdx.x;
    if (b < 256) {
        int type = b >> 7, tb = b & 127;
        int ki = tb >> 2, ci = tb & 3;
        const float* src = fW0 + (size_t)type * 131072;
        int c = tid & 31, r0 = (tid >> 5) * 4;
        #pragma unroll
        for (int q = 0; q < 4; q++)
            s_t[r0 + q][c] = src[(size_t)(ki * 32 + r0 + q) * 128 + ci * 32 + c];
        __syncthreads();
        _Float16* dst = W0ht + (size_t)type * 131072;
        int kk = tid & 31, c0 = (tid >> 5) * 4;
        #pragma unroll
        for (int q = 0; q < 4; q++)
            dst[(size_t)(ci * 32 + c0 + q) * 1024 + ki * 32 + kk] = (_Float16)s_t[kk][c0 + q];
    } else {
        int b2v = b - 256;           // 0..31
        int type = b2v >> 4, tb = b2v & 15;
        int ki = tb >> 2, ci = tb & 3;
        const float* src = fW1 + (size_t)type * 16384;
        int c = tid & 31, r0 = (tid >> 5) * 4;
        #pragma unroll
        for (int q = 0; q < 4; q++)
            s_t[r0 + q][c] = src[(size_t)(ki * 32 + r0 + q) * 128 + ci * 32 + c];
        __syncthreads();
        _Float16* dst = W1ht + (size_t)type * 16384;
        int kk = tid & 31, c0 = (tid >> 5) * 4;
        #pragma unroll
        for (int q = 0; q < 4; q++)
            dst[(size_t)(ci * 32 + c0 + q) * 128 + ki * 32 + kk] = (_Float16)s_t[kk][c0 + q];
    }
}

// ---------------- Kernel 2: fit net as MFMA GEMM (64 atoms / block) ---------
// 512 thr = 8 waves: wave = (mt = w>>1 rows 16mt.., nh = w&1 cols 64nh..)
// LDS tiles XOR-swizzled in 16B units: unit' = unit ^ (row & 15)
__global__ __launch_bounds__(512) void k_fit(
    const _Float16* __restrict__ featf, const _Float16* __restrict__ W0ht,
    const _Float16* __restrict__ W1ht,
    const float* __restrict__ b0, const float* __restrict__ b1,
    const float* __restrict__ W2, const float* __restrict__ b2,
    const float* __restrict__ Ebias, const int* __restrict__ n1p,
    float* __restrict__ out)
{
    __shared__ _Float16 s_A[64 * 128];    // feat K-tile  [row][k]   16 KB
    __shared__ _Float16 s_B[128 * 128];   // weight tile  [c][k]     32 KB
    __shared__ _Float16 s_h[64 * 128];    // layer-0 out  [row][c]   16 KB
    __shared__ float s_part[8];

    const int tid  = threadIdx.x;
    const int lane = tid & 63, w = tid >> 6;
    const int mt = w >> 1, nh = w & 1;
    const int l15 = lane & 15, lk = lane >> 4;
    const int n0 = blockIdx.x * 64;
    const int n1 = *n1p;
    const int ia = (n0 >= n1) ? 1 : 0;

    const _Float16* W0t = W0ht + (size_t)ia * 131072;
    const _Float16* W1t = W1ht + (size_t)ia * 16384;

    f4 acc[4];
    #pragma unroll
    for (int nt = 0; nt < 4; nt++) acc[nt] = (f4)0.0f;

    // ---- layer 0: 8 K-tiles of 128 ----
    for (int kt = 0; kt < 8; kt++) {
        __syncthreads();
        {   // stage A: 64 rows x 128 f16
            int r = tid >> 3, ub = (tid & 7) * 2;
            const h8* g = (const h8*)(featf + (size_t)(n0 + r) * 1024 + kt * 128);
            #pragma unroll
            for (int q = 0; q < 2; q++) {
                int u = ub + q;
                *(h8*)&s_A[r * 128 + ((u ^ (r & 15)) << 3)] = g[u];
            }
        }
        {   // stage B: 128 cols x 128 f16 (W0ht rows are contiguous in k)
            int c = tid >> 2, ub = (tid & 3) * 4;
            const h8* g = (const h8*)(W0t + (size_t)c * 1024 + kt * 128);
            #pragma unroll
            for (int q = 0; q < 4; q++) {
                int u = ub + q;
                *(h8*)&s_B[c * 128 + ((u ^ (c & 15)) << 3)] = g[u];
            }
        }
        __syncthreads();
        #pragma unroll
        for (int ks = 0; ks < 4; ks++) {
            const int row = mt * 16 + l15;
            h8 a = *(const h8*)&s_A[row * 128 + (((ks * 4 + lk) ^ (row & 15)) << 3)];
            #pragma unroll
            for (int nt = 0; nt < 4; nt++) {
                const int c = nh * 64 + nt * 16 + l15;
                h8 bfr = *(const h8*)&s_B[c * 128 + (((ks * 4 + lk) ^ (c & 15)) << 3)];
                acc[nt] = __builtin_amdgcn_mfma_f32_16x16x32_f16(a, bfr, acc[nt], 0, 0, 0);
            }
        }
    }

    // ---- layer-0 epilogue: bias + tanh -> s_h (fp16, swizzled) ----
    #pragma unroll
    for (int nt = 0; nt < 4; nt++) {
        const int c = nh * 64 + nt * 16 + l15;
        const float bias = b0[ia * 128 + c];
        #pragma unroll
        for (int r = 0; r < 4; r++) {
            const int row = mt * 16 + lk * 4 + r;
            float v = fast_tanh(acc[nt][r] + bias);
            s_h[row * 128 + (((c >> 3) ^ (row & 15)) << 3) + (c & 7)] = (_Float16)v;
        }
    }
    __syncthreads();
    {   // stage W1 into s_B
        int c = tid >> 2, ub = (tid & 3) * 4;
        const h8* g = (const h8*)(W1t + (size_t)c * 128);
        #pragma unroll
        for (int q = 0; q < 4; q++) {
            int u = ub + q;
            *(h8*)&s_B[c * 128 + ((u ^ (c & 15)) << 3)] = g[u];
        }
    }
    __syncthreads();

    // ---- layer 1: K = 128 ----
    f4 acc1[4];
    #pragma unroll
    for (int nt = 0; nt < 4; nt++) acc1[nt] = (f4)0.0f;
    #pragma unroll
    for (int ks = 0; ks < 4; ks++) {
        const int row = mt * 16 + l15;
        h8 a = *(const h8*)&s_h[row * 128 + (((ks * 4 + lk) ^ (row & 15)) << 3)];
        #pragma unroll
        for (int nt = 0; nt < 4; nt++) {
            const int c = nh * 64 + nt * 16 + l15;
            h8 bfr = *(const h8*)&s_B[c * 128 + (((ks * 4 + lk) ^ (c & 15)) << 3)];
            acc1[nt] = __builtin_amdgcn_mfma_f32_16x16x32_f16(a, bfr, acc1[nt], 0, 0, 0);
        }
    }

    // ---- layer 2 + energy reduction ----
    float p = 0.0f;
    #pragma unroll
    for (int nt = 0; nt < 4; nt++) {
        const int c = nh * 64 + nt * 16 + l15;
        const float bias = b1[ia * 128 + c];
        const float w2v  = W2[ia * 128 + c];
        #pragma unroll
        for (int r = 0; r < 4; r++)
            p += fast_tanh(acc1[nt][r] + bias) * w2v;
    }
    #pragma unroll
    for (int m = 1; m < 64; m <<= 1) p += __shfl_xor(p, m);
    if (lane == 0) s_part[w] = p;
    __syncthreads();
    if (tid == 0) {
        float e = ((s_part[0] + s_part[1]) + (s_part[2] + s_part[3]))
                + ((s_part[4] + s_part[5]) + (s_part[6] + s_part[7]))
                + 64.0f * (b2[ia] + Ebias[ia]);
        atomicAdd(out, e);
    }
}

extern "C" void kernel_launch(void* const* d_in, const int* in_sizes, int n_in,
                              void* d_out, int out_size, void* d_ws, size_t ws_size,
                              hipStream_t stream) {
    const float* coord   = (const float*)d_in[0];
    const float* box     = (const float*)d_in[1];
    const float* srmean  = (const float*)d_in[2];
    const float* srstd   = (const float*)d_in[3];
    const float* xrsrstd = (const float*)d_in[4];
    const float* Gbias   = (const float*)d_in[5];
    const float* Ebias   = (const float*)d_in[6];
    const float* eW0     = (const float*)d_in[7];
    const float* eb0     = (const float*)d_in[8];
    const float* eW1     = (const float*)d_in[9];
    const float* eb1     = (const float*)d_in[10];
    const float* eW2     = (const float*)d_in[11];
    const float* eb2     = (const float*)d_in[12];
    const float* fW0     = (const float*)d_in[13];
    const float* fb0     = (const float*)d_in[14];
    const float* fW1     = (const float*)d_in[15];
    const float* fb1     = (const float*)d_in[16];
    const float* fW2     = (const float*)d_in[17];
    const float* fb2     = (const float*)d_in[18];
    const int*   n1p     = (const int*)d_in[19];

    const int N = in_sizes[0] / 3;          // 1024
    h2* featbuf = (h2*)d_ws;                          // N*512 h2 = 2 MB
    _Float16* W0ht = (_Float16*)((char*)d_ws + (size_t)2 * 1024 * 1024);  // 512 KB
    _Float16* W1ht = W0ht + 2 * 131072;                                   // 64 KB

    (void)hipMemsetAsync(d_out, 0, sizeof(float), stream);
    k_prep<<<288, 256, 0, stream>>>(fW0, fW1, W0ht, W1ht);
    k_embed<<<N, 256, 0, stream>>>(coord, box, srmean, srstd, xrsrstd, Gbias,
                                   eW0, eb0, eW1, eb1, eW2, eb2, n1p, featbuf, N);
    k_fit<<<N / 64, 512, 0, stream>>>((const _Float16*)featbuf, W0ht, W1ht,
                                      fb0, fb1, fW2, fb2, Ebias, n1p, (float*)d_out);
}

// Round 8
// 41.039 us; speedup vs baseline: 1.9294x; 1.1665x over previous
//
#include <hip/hip_runtime.h>

#define RCUT 6.0f

typedef _Float16 h2 __attribute__((ext_vector_type(2)));
typedef _Float16 h8 __attribute__((ext_vector_type(8)));
typedef float    f4 __attribute__((ext_vector_type(4)));

__device__ __forceinline__ float fast_tanh(float x) {
    float e = __expf(2.0f * x);              // inf for large x -> tanh=1
    return 1.0f - 2.0f * __builtin_amdgcn_rcpf(e + 1.0f);
}

__device__ __forceinline__ h2 pkh(float a, float b) {
#if __has_builtin(__builtin_amdgcn_cvt_pkrtz)
    union { __fp16 __attribute__((ext_vector_type(2))) r; h2 h; } u;
    u.r = __builtin_amdgcn_cvt_pkrtz(a, b);
    return u.h;
#else
    h2 r; r.x = (_Float16)a; r.y = (_Float16)b; return r;
#endif
}

// ---- Kernel 1: neighbor scan + embed MLP (W1, W2, stage2 all via MFMA) -----
// Blocks [0,N): one atom each. Blocks [N, N+288): fit-weight transpose prep.
__global__ __launch_bounds__(256, 4) void k_embed(
    const float* __restrict__ coord, const float* __restrict__ box,
    const float* __restrict__ srmean, const float* __restrict__ srstd,
    const float* __restrict__ xrsrstd, const float* __restrict__ Gbias,
    const float* __restrict__ eW0, const float* __restrict__ eb0,
    const float* __restrict__ eW1, const float* __restrict__ eb1,
    const float* __restrict__ eW2, const float* __restrict__ eb2,
    const int* __restrict__ n1p,
    const float* __restrict__ fW0, const float* __restrict__ fW1,
    h2* __restrict__ feat, _Float16* __restrict__ W0ht,
    _Float16* __restrict__ W1ht, unsigned int* __restrict__ counter, int N)
{
    const int nb  = blockIdx.x;
    const int tid = threadIdx.x;

    __shared__ struct { float w0[2][16], b0[2][16]; } sw;
    __shared__ _Float16 s_h0[128][24];     // h0 rows (16 f16 + pad to 48B)
    __shared__ _Float16 s_h1[128][40];     // h1 rows (32 f16 + pad to 80B)
    __shared__ __align__(16) _Float16 s_ef[4][4][64][8]; // e in B-frag layout
    __shared__ float s_coef[4][128];       // srbias, Rx, Ry, Rz per pair
    __shared__ unsigned short s_nbr[512];
    __shared__ float s_g4[256];            // G[4][64]
    __shared__ int   s_wcnt[4], s_wcnt0[4];

    // ================= prep path: transpose+fp16 fit weights =================
    if (nb >= N) {
        const int b = nb - N;
        if (b == 0 && tid == 0) *counter = 0u;
        float (*s_t)[33] = reinterpret_cast<float(*)[33]>(&s_ef[0][0][0][0]);
        if (b < 256) {
            int type = b >> 7, tb = b & 127;
            int ki = tb >> 2, ci = tb & 3;
            const float* src = fW0 + (size_t)type * 131072;
            int c = tid & 31, r0 = (tid >> 5) * 4;
            #pragma unroll
            for (int q = 0; q < 4; q++)
                s_t[r0 + q][c] = src[(size_t)(ki * 32 + r0 + q) * 128 + ci * 32 + c];
            __syncthreads();
            _Float16* dst = W0ht + (size_t)type * 131072;
            int kk = tid & 31, c0 = (tid >> 5) * 4;
            #pragma unroll
            for (int q = 0; q < 4; q++)
                dst[(size_t)(ci * 32 + c0 + q) * 1024 + ki * 32 + kk] = (_Float16)s_t[kk][c0 + q];
        } else {
            int b2v = b - 256;           // 0..31
            int type = b2v >> 4, tb = b2v & 15;
            int ki = tb >> 2, ci = tb & 3;
            const float* src = fW1 + (size_t)type * 16384;
            int c = tid & 31, r0 = (tid >> 5) * 4;
            #pragma unroll
            for (int q = 0; q < 4; q++)
                s_t[r0 + q][c] = src[(size_t)(ki * 32 + r0 + q) * 128 + ci * 32 + c];
            __syncthreads();
            _Float16* dst = W1ht + (size_t)type * 16384;
            int kk = tid & 31, c0 = (tid >> 5) * 4;
            #pragma unroll
            for (int q = 0; q < 4; q++)
                dst[(size_t)(ci * 32 + c0 + q) * 128 + ki * 32 + kk] = (_Float16)s_t[kk][c0 + q];
        }
        return;
    }

    // ================= main path: one atom per block =========================
    const int n  = nb;
    const int n1 = *n1p;
    const int ti = (n >= n1) ? 1 : 0;

    for (int t = tid; t < 32; t += 256) { int j = t >> 4, f = t & 15;
        sw.w0[j][f] = eW0[(2 * ti + j) * 16 + f];
        sw.b0[j][f] = eb0[(2 * ti + j) * 16 + f]; }

    const int wid = tid >> 6, lane = tid & 63;
    const int l15 = lane & 15, lk = lane >> 4;

    // ---- W2 B-fragments + b2 into registers ----
    h8 bf[2][4];
    float b2r[2][4];
    #pragma unroll
    for (int j = 0; j < 2; j++) {
        const float* w2g = eW2 + (size_t)(2 * ti + j) * 2048;
        #pragma unroll
        for (int nt = 0; nt < 4; nt++) {
            h8 v;
            #pragma unroll
            for (int r = 0; r < 8; r++)
                v[r] = (_Float16)w2g[(8 * lk + r) * 64 + nt * 16 + l15];
            bf[j][nt] = v;
            b2r[j][nt] = eb2[(2 * ti + j) * 64 + nt * 16 + l15];
        }
    }
    // ---- W1 B-fragments (K padded 16->32 with zeros) + b1 into registers ----
    h8 w1f[2][2];
    float b1r[2][2];
    #pragma unroll
    for (int j = 0; j < 2; j++) {
        const float* w1g = eW1 + (size_t)(2 * ti + j) * 512;
        #pragma unroll
        for (int nt1 = 0; nt1 < 2; nt1++) {
            h8 v = {};
            if (lk < 2) {
                #pragma unroll
                for (int r = 0; r < 8; r++)
                    v[r] = (_Float16)w1g[(8 * lk + r) * 32 + 16 * nt1 + l15];
            }
            w1f[j][nt1] = v;
            b1r[j][nt1] = eb1[(2 * ti + j) * 32 + 16 * nt1 + l15];
        }
    }

    const float Lx = box[0], Ly = box[4], Lz = box[8];
    const float iLx = 1.0f / Lx, iLy = 1.0f / Ly, iLz = 1.0f / Lz;
    const float xn = coord[n], yn = coord[N + n], zn = coord[2 * N + n];

    // ---- parallel deterministic neighbor scan (m ascending => type-sorted) --
    {
        unsigned long long bal[4];
        int wtotal = 0, wtotal0 = 0;
        const int mystart = wid * 256;
        #pragma unroll
        for (int r = 0; r < 4; r++) {
            int m = mystart + r * 64 + lane;
            float dx = coord[m] - xn;         dx -= Lx * rintf(dx * iLx);
            float dy = coord[N + m] - yn;     dy -= Ly * rintf(dy * iLy);
            float dz = coord[2 * N + m] - zn; dz -= Lz * rintf(dz * iLz);
            float r2 = dx * dx + dy * dy + dz * dz;
            bool pred = (r2 < RCUT * RCUT) && (m != n);
            bal[r] = __ballot(pred);
            unsigned long long bal0 = __ballot(pred && (m < n1));
            wtotal  += (int)__popcll(bal[r]);
            wtotal0 += (int)__popcll(bal0);
        }
        if (lane == 0) { s_wcnt[wid] = wtotal; s_wcnt0[wid] = wtotal0; }
        __syncthreads();
        int base = 0;
        for (int w = 0; w < wid; w++) base += s_wcnt[w];
        #pragma unroll
        for (int r = 0; r < 4; r++) {
            bool pred = (bal[r] >> lane) & 1ull;
            int pos = (int)__popcll(bal[r] & ((1ull << lane) - 1ull));
            if (pred && (base + pos) < 512)
                s_nbr[base + pos] = (unsigned short)(wid * 256 + r * 64 + lane);
            base += (int)__popcll(bal[r]);
        }
    }
    __syncthreads();
    int cnt  = s_wcnt[0] + s_wcnt[1] + s_wcnt[2] + s_wcnt[3];
    int cnt0 = s_wcnt0[0] + s_wcnt0[1] + s_wcnt0[2] + s_wcnt0[3];
    if (cnt > 512) cnt = 512;

    const float srm  = srmean[ti];
    const float isrs = 1.0f / srstd[ti];
    const float ixrs = 1.0f / xrsrstd[ti];

    const int p  = tid & 127;   // stage-1 pair slot
    const int hh = tid >> 7;    // stage-1 h0-half (f = 8*hh..8*hh+7)
    const int dummy = (n + 1 < N) ? (n + 1) : 0;

    f4 gacc = {0.0f, 0.0f, 0.0f, 0.0f};
    const f4 zf4 = {0.0f, 0.0f, 0.0f, 0.0f};

    const int ntiles = (cnt + 127) >> 7;
    for (int t = 0; t < ntiles; t++) {
        const int t128 = t << 7;
        __syncthreads();   // B1: protect s_h0/s_h1/s_ef/s_coef from prev readers
        {   // ---- stage 1a: geometry + coeffs + h0 (8 tanh per thread) ----
            const int pi = t128 + p;
            const bool valid = pi < cnt;
            int m = valid ? (int)s_nbr[pi] : dummy;
            float dx = coord[m] - xn;         dx -= Lx * rintf(dx * iLx);
            float dy = coord[N + m] - yn;     dy -= Ly * rintf(dy * iLy);
            float dz = coord[2 * N + m] - zn; dz -= Lz * rintf(dz * iLz);
            float r2 = dx * dx + dy * dy + dz * dz;
            float r  = sqrtf(r2);
            float rinv = __builtin_amdgcn_rcpf(r);
            float u  = r * (1.0f / RCUT);
            float u3 = u * u * u;
            float sw_ = ((-6.0f * u + 15.0f) * u - 10.0f) * u3 + 1.0f;
            if (!valid) sw_ = 0.0f;
            float sr  = sw_ * rinv;
            float srn = (sr - srm) * isrs;
            if (hh == 0) {
                float csr = valid ? sr * isrs : 0.0f;
                float crs = valid ? (sr * rinv * ixrs + 1e-15f) : 0.0f;
                s_coef[0][p] = csr;
                s_coef[1][p] = crs * dx;
                s_coef[2][p] = crs * dy;
                s_coef[3][p] = crs * dz;
            }
            const int j = (m >= n1) ? 1 : 0;
            h8 v;
            #pragma unroll
            for (int q = 0; q < 8; q++) {
                int f = 8 * hh + q;
                v[q] = (_Float16)fast_tanh(fmaf(srn, sw.w0[j][f], sw.b0[j][f]));
            }
            *(h8*)&s_h0[p][8 * hh] = v;
        }
        __syncthreads();   // B2: s_h0 + s_coef ready

        // ---- W1 via MFMA: h1[128][32] = tanh(h0[128][16pad32] @ W1 + b1) ----
        {
            #pragma unroll
            for (int mt2 = 0; mt2 < 2; mt2++) {
                const int mt  = 2 * wid + mt2;
                const int row = 16 * mt + l15;
                h8 a = {};
                if (lk < 2) a = *(const h8*)&s_h0[row][8 * lk];
                const int gpb = 16 * mt;
                const bool need0 = (t128 + gpb) < cnt0;
                const bool need1 = (t128 + gpb + 15) >= cnt0;
                #pragma unroll
                for (int nt1 = 0; nt1 < 2; nt1++) {
                    f4 d0 = zf4, d1 = zf4;
                    if (need0) d0 = __builtin_amdgcn_mfma_f32_16x16x32_f16(a, w1f[0][nt1], zf4, 0, 0, 0);
                    if (need1) d1 = __builtin_amdgcn_mfma_f32_16x16x32_f16(a, w1f[1][nt1], zf4, 0, 0, 0);
                    #pragma unroll
                    for (int r = 0; r < 4; r++) {
                        int gp = gpb + 4 * lk + r;
                        bool is0 = (t128 + gp) < cnt0;
                        float dv = is0 ? d0[r] : d1[r];
                        float hv = fast_tanh(dv + (is0 ? b1r[0][nt1] : b1r[1][nt1]));
                        s_h1[gp][16 * nt1 + l15] = (_Float16)hv;
                    }
                }
            }
        }
        __syncthreads();   // B2b: s_h1 ready

        // ---- W2 via MFMA: e[128][64] = tanh(h1[128][32] @ W2[32][64] + b2)
        {
            #pragma unroll
            for (int mt2 = 0; mt2 < 2; mt2++) {
                const int mt  = 2 * wid + mt2;
                const int row = 16 * mt + l15;
                h8 a = *(const h8*)&s_h1[row][8 * lk];
                const int gpb = 16 * mt;
                const bool need0 = (t128 + gpb) < cnt0;
                const bool need1 = (t128 + gpb + 15) >= cnt0;
                #pragma unroll
                for (int nt = 0; nt < 4; nt++) {
                    f4 d0 = zf4, d1 = zf4;
                    if (need0) d0 = __builtin_amdgcn_mfma_f32_16x16x32_f16(a, bf[0][nt], zf4, 0, 0, 0);
                    if (need1) d1 = __builtin_amdgcn_mfma_f32_16x16x32_f16(a, bf[1][nt], zf4, 0, 0, 0);
                    #pragma unroll
                    for (int r = 0; r < 4; r++) {
                        int gp = gpb + 4 * lk + r;
                        bool is0 = (t128 + gp) < cnt0;
                        float dv = is0 ? d0[r] : d1[r];
                        float ev = fast_tanh(dv + (is0 ? b2r[0][nt] : b2r[1][nt]));
                        s_ef[nt][gp >> 5][l15 + 16 * ((gp & 31) >> 3)][gp & 7] = (_Float16)ev;
                    }
                }
            }
        }
        __syncthreads();   // B3: s_ef ready

        // ---- stage 2 via MFMA: G[4pad16][64] += coef[4][128] @ e[128][64]
        {
            #pragma unroll
            for (int ks = 0; ks < 4; ks++) {
                h8 ac;
                #pragma unroll
                for (int r = 0; r < 8; r++) {
                    int kk = 32 * ks + 8 * lk + r;
                    float cv = (l15 < 4) ? s_coef[l15][kk] : 0.0f;
                    ac[r] = (_Float16)cv;
                }
                h8 eb = *(const h8*)&s_ef[wid][ks][lane][0];
                gacc = __builtin_amdgcn_mfma_f32_16x16x32_f16(ac, eb, gacc, 0, 0, 0);
            }
        }
    }

    // ---- epilogue: G rows live in lanes 0..15 (lk==0), regs r=k ----
    if (lane < 16) {
        #pragma unroll
        for (int r = 0; r < 4; r++) {
            float gv = gacc[r] * (1.0f / 64.0f);
            if (r == 0) gv += Gbias[16 * wid + lane];
            s_g4[r * 64 + 16 * wid + lane] = gv;
        }
    }
    __syncthreads();
    {
        h2* outp = feat + (size_t)n * 512;
        #pragma unroll
        for (int q = 0; q < 2; q++) {
            int o2 = tid + 256 * q;          // h2 index; elements 2*o2, 2*o2+1
            int a = o2 >> 5;
            int c = (2 * o2) & 63;
            float ga0 = s_g4[a],       ga1 = s_g4[64 + a];
            float ga2 = s_g4[128 + a], ga3 = s_g4[192 + a];
            float s0 = ga0 * s_g4[c];
            s0 = fmaf(ga1, s_g4[64 + c],  s0);
            s0 = fmaf(ga2, s_g4[128 + c], s0);
            s0 = fmaf(ga3, s_g4[192 + c], s0);
            float s1 = ga0 * s_g4[c + 1];
            s1 = fmaf(ga1, s_g4[64 + c + 1],  s1);
            s1 = fmaf(ga2, s_g4[128 + c + 1], s1);
            s1 = fmaf(ga3, s_g4[192 + c + 1], s1);
            outp[o2] = pkh(s0, s1);
        }
    }
}

// ---------------- Kernel 2: fit net as MFMA GEMM (64 atoms / block) ---------
__global__ __launch_bounds__(512) void k_fit(
    const _Float16* __restrict__ featf, const _Float16* __restrict__ W0ht,
    const _Float16* __restrict__ W1ht,
    const float* __restrict__ b0, const float* __restrict__ b1,
    const float* __restrict__ W2, const float* __restrict__ b2,
    const float* __restrict__ Ebias, const int* __restrict__ n1p,
    unsigned int* __restrict__ counter, float* __restrict__ slots,
    float* __restrict__ out)
{
    __shared__ _Float16 s_A[64 * 128];    // feat K-tile  [row][k]   16 KB
    __shared__ _Float16 s_B[128 * 128];   // weight tile  [c][k]     32 KB
    __shared__ _Float16 s_h[64 * 128];    // layer-0 out  [row][c]   16 KB
    __shared__ float s_part[8];

    const int tid  = threadIdx.x;
    const int lane = tid & 63, w = tid >> 6;
    const int mt = w >> 1, nh = w & 1;
    const int l15 = lane & 15, lk = lane >> 4;
    const int n0 = blockIdx.x * 64;
    const int n1 = *n1p;
    const int ia = (n0 >= n1) ? 1 : 0;

    const _Float16* W0t = W0ht + (size_t)ia * 131072;
    const _Float16* W1t = W1ht + (size_t)ia * 16384;

    f4 acc[4];
    #pragma unroll
    for (int nt = 0; nt < 4; nt++) acc[nt] = (f4)0.0f;

    // ---- layer 0: 8 K-tiles of 128 ----
    for (int kt = 0; kt < 8; kt++) {
        __syncthreads();
        {   // stage A: 64 rows x 128 f16
            int r = tid >> 3, ub = (tid & 7) * 2;
            const h8* g = (const h8*)(featf + (size_t)(n0 + r) * 1024 + kt * 128);
            #pragma unroll
            for (int q = 0; q < 2; q++) {
                int u = ub + q;
                *(h8*)&s_A[r * 128 + ((u ^ (r & 15)) << 3)] = g[u];
            }
        }
        {   // stage B: 128 cols x 128 f16
            int c = tid >> 2, ub = (tid & 3) * 4;
            const h8* g = (const h8*)(W0t + (size_t)c * 1024 + kt * 128);
            #pragma unroll
            for (int q = 0; q < 4; q++) {
                int u = ub + q;
                *(h8*)&s_B[c * 128 + ((u ^ (c & 15)) << 3)] = g[u];
            }
        }
        __syncthreads();
        #pragma unroll
        for (int ks = 0; ks < 4; ks++) {
            const int row = mt * 16 + l15;
            h8 a = *(const h8*)&s_A[row * 128 + (((ks * 4 + lk) ^ (row & 15)) << 3)];
            #pragma unroll
            for (int nt = 0; nt < 4; nt++) {
                const int c = nh * 64 + nt * 16 + l15;
                h8 bfr = *(const h8*)&s_B[c * 128 + (((ks * 4 + lk) ^ (c & 15)) << 3)];
                acc[nt] = __builtin_amdgcn_mfma_f32_16x16x32_f16(a, bfr, acc[nt], 0, 0, 0);
            }
        }
    }

    // ---- layer-0 epilogue: bias + tanh -> s_h (fp16, swizzled) ----
    #pragma unroll
    for (int nt = 0; nt < 4; nt++) {
        const int c = nh * 64 + nt * 16 + l15;
        const float bias = b0[ia * 128 + c];
        #pragma unroll
        for (int r = 0; r < 4; r++) {
            const int row = mt * 16 + lk * 4 + r;
            float v = fast_tanh(acc[nt][r] + bias);
            s_h[row * 128 + (((c >> 3) ^ (row & 15)) << 3) + (c & 7)] = (_Float16)v;
        }
    }
    __syncthreads();
    {   // stage W1 into s_B
        int c = tid >> 2, ub = (tid & 3) * 4;
        const h8* g = (const h8*)(W1t + (size_t)c * 128);
        #pragma unroll
        for (int q = 0; q < 4; q++) {
            int u = ub + q;
            *(h8*)&s_B[c * 128 + ((u ^ (c & 15)) << 3)] = g[u];
        }
    }
    __syncthreads();

    // ---- layer 1: K = 128 ----
    f4 acc1[4];
    #pragma unroll
    for (int nt = 0; nt < 4; nt++) acc1[nt] = (f4)0.0f;
    #pragma unroll
    for (int ks = 0; ks < 4; ks++) {
        const int row = mt * 16 + l15;
        h8 a = *(const h8*)&s_h[row * 128 + (((ks * 4 + lk) ^ (row & 15)) << 3)];
        #pragma unroll
        for (int nt = 0; nt < 4; nt++) {
            const int c = nh * 64 + nt * 16 + l15;
            h8 bfr = *(const h8*)&s_B[c * 128 + (((ks * 4 + lk) ^ (c & 15)) << 3)];
            acc1[nt] = __builtin_amdgcn_mfma_f32_16x16x32_f16(a, bfr, acc1[nt], 0, 0, 0);
        }
    }

    // ---- layer 2 + deterministic cross-block energy reduction ----
    float p = 0.0f;
    #pragma unroll
    for (int nt = 0; nt < 4; nt++) {
        const int c = nh * 64 + nt * 16 + l15;
        const float bias = b1[ia * 128 + c];
        const float w2v  = W2[ia * 128 + c];
        #pragma unroll
        for (int r = 0; r < 4; r++)
            p += fast_tanh(acc1[nt][r] + bias) * w2v;
    }
    #pragma unroll
    for (int m = 1; m < 64; m <<= 1) p += __shfl_xor(p, m);
    if (lane == 0) s_part[w] = p;
    __syncthreads();
    if (tid == 0) {
        float e = ((s_part[0] + s_part[1]) + (s_part[2] + s_part[3]))
                + ((s_part[4] + s_part[5]) + (s_part[6] + s_part[7]))
                + 64.0f * (b2[ia] + Ebias[ia]);
        slots[blockIdx.x] = e;
        __threadfence();
        unsigned int old = atomicAdd(counter, 1u);
        if (old == 15u) {
            __threadfence();
            float tot = 0.0f;
            #pragma unroll
            for (int i = 0; i < 16; i++)
                tot += __hip_atomic_load(&slots[i], __ATOMIC_RELAXED, __HIP_MEMORY_SCOPE_AGENT);
            out[0] = tot;
        }
    }
}

extern "C" void kernel_launch(void* const* d_in, const int* in_sizes, int n_in,
                              void* d_out, int out_size, void* d_ws, size_t ws_size,
                              hipStream_t stream) {
    const float* coord   = (const float*)d_in[0];
    const float* box     = (const float*)d_in[1];
    const float* srmean  = (const float*)d_in[2];
    const float* srstd   = (const float*)d_in[3];
    const float* xrsrstd = (const float*)d_in[4];
    const float* Gbias   = (const float*)d_in[5];
    const float* Ebias   = (const float*)d_in[6];
    const float* eW0     = (const float*)d_in[7];
    const float* eb0     = (const float*)d_in[8];
    const float* eW1     = (const float*)d_in[9];
    const float* eb1     = (const float*)d_in[10];
    const float* eW2     = (const float*)d_in[11];
    const float* eb2     = (const float*)d_in[12];
    const float* fW0     = (const float*)d_in[13];
    const float* fb0     = (const float*)d_in[14];
    const float* fW1     = (const float*)d_in[15];
    const float* fb1     = (const float*)d_in[16];
    const float* fW2     = (const float*)d_in[17];
    const float* fb2     = (const float*)d_in[18];
    const int*   n1p     = (const int*)d_in[19];

    const int N = in_sizes[0] / 3;          // 1024
    h2*       featbuf = (h2*)d_ws;                                        // 2 MB
    _Float16* W0ht = (_Float16*)((char*)d_ws + (size_t)2 * 1024 * 1024);  // 512 KB
    _Float16* W1ht = W0ht + 2 * 131072;                                   // 64 KB
    char* tail = (char*)d_ws + (size_t)(2 * 1024 + 512 + 64) * 1024;
    unsigned int* counter = (unsigned int*)tail;
    float*        slots   = (float*)(tail + 64);

    k_embed<<<N + 288, 256, 0, stream>>>(coord, box, srmean, srstd, xrsrstd, Gbias,
                                         eW0, eb0, eW1, eb1, eW2, eb2, n1p,
                                         fW0, fW1, featbuf, W0ht, W1ht, counter, N);
    k_fit<<<N / 64, 512, 0, stream>>>((const _Float16*)featbuf, W0ht, W1ht,
                                      fb0, fb1, fW2, fb2, Ebias, n1p,
                                      counter, slots, (float*)d_out);
}

// Round 9
// 39.418 us; speedup vs baseline: 2.0087x; 1.0411x over previous
//
#include <hip/hip_runtime.h>

#define RCUT 6.0f

typedef _Float16 h2v __attribute__((ext_vector_type(2)));
typedef _Float16 h8  __attribute__((ext_vector_type(8)));
typedef float    f4  __attribute__((ext_vector_type(4)));

__device__ __forceinline__ float fast_tanh(float x) {
    float e = __expf(2.0f * x);              // inf for large x -> tanh=1
    return 1.0f - 2.0f * __builtin_amdgcn_rcpf(e + 1.0f);
}

__device__ __forceinline__ h2v pkh(float a, float b) {
#if __has_builtin(__builtin_amdgcn_cvt_pkrtz)
    union { __fp16 __attribute__((ext_vector_type(2))) r; h2v h; } u;
    u.r = __builtin_amdgcn_cvt_pkrtz(a, b);
    return u.h;
#else
    h2v r; r.x = (_Float16)a; r.y = (_Float16)b; return r;
#endif
}

// ---- Kernel 1: 2 atoms/block; scan precomputes coefs; W1+W2+stage2 MFMA ----
// Blocks [0, NB): atom pair (2b, 2b+1). Blocks [NB, NB+288): fit-weight prep.
__global__ __launch_bounds__(256, 3) void k_embed(
    const float* __restrict__ coord, const float* __restrict__ box,
    const float* __restrict__ srmean, const float* __restrict__ srstd,
    const float* __restrict__ xrsrstd, const float* __restrict__ Gbias,
    const float* __restrict__ eW0, const float* __restrict__ eb0,
    const float* __restrict__ eW1, const float* __restrict__ eb1,
    const float* __restrict__ eW2, const float* __restrict__ eb2,
    const int* __restrict__ n1p,
    const float* __restrict__ fW0, const float* __restrict__ fW1,
    h2v* __restrict__ feat, _Float16* __restrict__ W0ht,
    _Float16* __restrict__ W1ht, unsigned int* __restrict__ counter, int N)
{
    const int nb  = blockIdx.x;
    const int tid = threadIdx.x;
    const int NB  = N >> 1;

    __shared__ float s_w0[2][16], s_b0[2][16];
    __shared__ __align__(16) _Float16 s_srn[1024];      // 2 KB
    __shared__ __align__(16) _Float16 s_cf[4][1024];    // 8 KB  per-pair coefs
    __shared__ __align__(16) _Float16 s_h1[128][32];    // 8 KB  (XOR-swizzled units)
    __shared__ __align__(16) _Float16 s_ef[4][4][64][8];// 16 KB e in B-frag layout
    __shared__ unsigned short s_nbr[1024];              // 2 KB
    __shared__ float s_g4[2][256];                      // 2 KB  G for both atoms
    __shared__ __align__(16) _Float16 w1t[2][32][24];   // 3 KB  [j][c][k(16)+pad]
    __shared__ __align__(16) _Float16 w2t[2][64][40];   // 10 KB [j][c][k(32)+pad]
    __shared__ int s_wA[4], s_wB[4];

    // ================= prep path: transpose+fp16 fit weights =================
    if (nb >= NB) {
        const int b = nb - NB;
        if (b == 0 && tid == 0) *counter = 0u;
        float (*s_t)[33] = reinterpret_cast<float(*)[33]>(&s_ef[0][0][0][0]);
        if (b < 256) {
            int type = b >> 7, tb = b & 127;
            int ki = tb >> 2, ci = tb & 3;
            const float* src = fW0 + (size_t)type * 131072;
            int c = tid & 31, r0 = (tid >> 5) * 4;
            #pragma unroll
            for (int q = 0; q < 4; q++)
                s_t[r0 + q][c] = src[(size_t)(ki * 32 + r0 + q) * 128 + ci * 32 + c];
            __syncthreads();
            _Float16* dst = W0ht + (size_t)type * 131072;
            int kk = tid & 31, c0 = (tid >> 5) * 4;
            #pragma unroll
            for (int q = 0; q < 4; q++)
                dst[(size_t)(ci * 32 + c0 + q) * 1024 + ki * 32 + kk] = (_Float16)s_t[kk][c0 + q];
        } else {
            int b2v = b - 256, type = b2v >> 4, tb = b2v & 15;
            int ki = tb >> 2, ci = tb & 3;
            const float* src = fW1 + (size_t)type * 16384;
            int c = tid & 31, r0 = (tid >> 5) * 4;
            #pragma unroll
            for (int q = 0; q < 4; q++)
                s_t[r0 + q][c] = src[(size_t)(ki * 32 + r0 + q) * 128 + ci * 32 + c];
            __syncthreads();
            _Float16* dst = W1ht + (size_t)type * 16384;
            int kk = tid & 31, c0 = (tid >> 5) * 4;
            #pragma unroll
            for (int q = 0; q < 4; q++)
                dst[(size_t)(ci * 32 + c0 + q) * 128 + ki * 32 + kk] = (_Float16)s_t[kk][c0 + q];
        }
        return;
    }

    // ================= main path =================
    const int nA = 2 * nb, nBt = 2 * nb + 1;
    const int n1 = *n1p;
    const int ti = (nA >= n1) ? 1 : 0;
    const int wid = tid >> 6, lane = tid & 63;
    const int l15 = lane & 15, lk = lane >> 4;

    // ---- coalesced weight staging into LDS ----
    for (int t = tid; t < 32; t += 256) { int j = t >> 4, f = t & 15;
        s_w0[j][f] = eW0[(2 * ti + j) * 16 + f];
        s_b0[j][f] = eb0[(2 * ti + j) * 16 + f]; }
    for (int idx = tid; idx < 1024; idx += 256) {        // W1: [j][g(c)][f(k)]
        int j = idx >> 9, r = idx & 511, f = r >> 5, g = r & 31;
        w1t[j][g][f] = (_Float16)eW1[(2 * ti + j) * 512 + f * 32 + g];
    }
    for (int idx = tid; idx < 4096; idx += 256) {        // W2: [j][c][g(k)]
        int j = idx >> 11, r = idx & 2047, g = r >> 6, c = r & 63;
        w2t[j][c][g] = (_Float16)eW2[(2 * ti + j) * 2048 + g * 64 + c];
    }
    // per-lane bias registers
    float b1r[2][2], b2r[2][4];
    #pragma unroll
    for (int j = 0; j < 2; j++) {
        #pragma unroll
        for (int q = 0; q < 2; q++) b1r[j][q] = eb1[(2 * ti + j) * 32 + 16 * q + l15];
        #pragma unroll
        for (int q = 0; q < 4; q++) b2r[j][q] = eb2[(2 * ti + j) * 64 + 16 * q + l15];
    }

    const float Lx = box[0], Ly = box[4], Lz = box[8];
    const float iLx = 1.0f / Lx, iLy = 1.0f / Ly, iLz = 1.0f / Lz;
    const float xA = coord[nA], yA = coord[N + nA], zA = coord[2 * N + nA];
    const float xB = coord[nBt], yB = coord[N + nBt], zB = coord[2 * N + nBt];
    const float srm  = srmean[ti];
    const float isrs = 1.0f / srstd[ti];
    const float ixrs = 1.0f / xrsrstd[ti];

    // ---- dual-center scan: pass 1 (ballots), pass 2 (write pair data) ----
    unsigned long long balA[4], balB[4];
    float dxA[4], dyA[4], dzA[4], r2A[4];
    float dxB[4], dyB[4], dzB[4], r2B[4];
    {
        int wA = 0, wB = 0;
        const int mystart = wid * 256;
        #pragma unroll
        for (int r = 0; r < 4; r++) {
            int m = mystart + r * 64 + lane;
            float x = coord[m], y = coord[N + m], z = coord[2 * N + m];
            float ax = x - xA; ax -= Lx * rintf(ax * iLx);
            float ay = y - yA; ay -= Ly * rintf(ay * iLy);
            float az = z - zA; az -= Lz * rintf(az * iLz);
            float ra = ax * ax + ay * ay + az * az;
            float bx = x - xB; bx -= Lx * rintf(bx * iLx);
            float by = y - yB; by -= Ly * rintf(by * iLy);
            float bz = z - zB; bz -= Lz * rintf(bz * iLz);
            float rb = bx * bx + by * by + bz * bz;
            dxA[r] = ax; dyA[r] = ay; dzA[r] = az; r2A[r] = ra;
            dxB[r] = bx; dyB[r] = by; dzB[r] = bz; r2B[r] = rb;
            bool pA = (ra < RCUT * RCUT) && (m != nA);
            bool pB = (rb < RCUT * RCUT) && (m != nBt);
            balA[r] = __ballot(pA);
            balB[r] = __ballot(pB);
            wA += (int)__popcll(balA[r]);
            wB += (int)__popcll(balB[r]);
        }
        if (lane == 0) { s_wA[wid] = wA; s_wB[wid] = wB; }
    }
    __syncthreads();
    int cntA = s_wA[0] + s_wA[1] + s_wA[2] + s_wA[3];
    int cntB = s_wB[0] + s_wB[1] + s_wB[2] + s_wB[3];
    int cnt  = cntA + cntB;
    if (cnt > 1024) cnt = 1024;
    if (cntA > 1024) cntA = 1024;
    {
        int baseA = 0, baseB = cntA;
        for (int w = 0; w < wid; w++) { baseA += s_wA[w]; baseB += s_wB[w]; }
        const unsigned long long lt = (1ull << lane) - 1ull;
        const int mystart = wid * 256;
        #pragma unroll
        for (int r = 0; r < 4; r++) {
            int m = mystart + r * 64 + lane;
            #pragma unroll
            for (int cc = 0; cc < 2; cc++) {
                unsigned long long bal = cc ? balB[r] : balA[r];
                int base = cc ? baseB : baseA;
                if ((bal >> lane) & 1ull) {
                    int pos = base + (int)__popcll(bal & lt);
                    if (pos < 1024) {
                        float dx = cc ? dxB[r] : dxA[r];
                        float dy = cc ? dyB[r] : dyA[r];
                        float dz = cc ? dzB[r] : dzA[r];
                        float r2 = cc ? r2B[r] : r2A[r];
                        float rr = sqrtf(r2);
                        float rinv = __builtin_amdgcn_rcpf(rr);
                        float u  = rr * (1.0f / RCUT);
                        float u3 = u * u * u;
                        float sw_ = ((-6.0f * u + 15.0f) * u - 10.0f) * u3 + 1.0f;
                        float sr  = sw_ * rinv;
                        float crs = sr * rinv * ixrs + 1e-15f;
                        s_srn[pos]   = (_Float16)((sr - srm) * isrs);
                        s_cf[0][pos] = (_Float16)(sr * isrs);
                        s_cf[1][pos] = (_Float16)(crs * dx);
                        s_cf[2][pos] = (_Float16)(crs * dy);
                        s_cf[3][pos] = (_Float16)(crs * dz);
                        s_nbr[pos]   = (unsigned short)m;
                    }
                }
                if (cc) baseB += (int)__popcll(bal);
                else    baseA += (int)__popcll(bal);
            }
        }
    }
    __syncthreads();
    const int ntiles = (cnt + 127) >> 7;
    // zero the tail so tail pairs yield finite e and zero coef
    for (int i = cnt + tid; i < ntiles * 128; i += 256) {
        s_srn[i] = (_Float16)0.0f; s_nbr[i] = 0;
        s_cf[0][i] = (_Float16)0.0f; s_cf[1][i] = (_Float16)0.0f;
        s_cf[2][i] = (_Float16)0.0f; s_cf[3][i] = (_Float16)0.0f;
    }
    __syncthreads();

    f4 gacc = {0.0f, 0.0f, 0.0f, 0.0f};
    const f4 zf4 = {0.0f, 0.0f, 0.0f, 0.0f};

    for (int t = 0; t < ntiles; t++) {
        const int t128 = t << 7;
        __syncthreads();   // B1: protect s_ef from previous stage-2 readers

        // ---- W1 (h0 inline) then W2, fused per wave (same-wave LDS deps) ----
        #pragma unroll
        for (int mt2 = 0; mt2 < 2; mt2++) {
            const int mt = 2 * wid + mt2;
            const int row = 16 * mt + l15;
            const int rp = t128 + row;
            float srn = (float)s_srn[rp];
            int jr = (s_nbr[rp] >= n1) ? 1 : 0;
            h8 a = {};
            if (lk < 2) {
                const float* wp = &s_w0[jr][8 * lk];
                const float* bp = &s_b0[jr][8 * lk];
                #pragma unroll
                for (int q = 0; q < 8; q++)
                    a[q] = (_Float16)fast_tanh(fmaf(srn, wp[q], bp[q]));
            }
            #pragma unroll
            for (int nt1 = 0; nt1 < 2; nt1++) {
                const int c = 16 * nt1 + l15;
                h8 b0f = {}, b1f = {};
                if (lk < 2) {
                    b0f = *(const h8*)&w1t[0][c][8 * lk];
                    b1f = *(const h8*)&w1t[1][c][8 * lk];
                }
                f4 d0 = __builtin_amdgcn_mfma_f32_16x16x32_f16(a, b0f, zf4, 0, 0, 0);
                f4 d1 = __builtin_amdgcn_mfma_f32_16x16x32_f16(a, b1f, zf4, 0, 0, 0);
                #pragma unroll
                for (int r = 0; r < 4; r++) {
                    int gp = 16 * mt + 4 * lk + r;
                    bool is0 = (s_nbr[t128 + gp] < n1);
                    float hv = fast_tanh((is0 ? d0[r] : d1[r]) + (is0 ? b1r[0][nt1] : b1r[1][nt1]));
                    int e = 16 * nt1 + l15;
                    s_h1[gp][(((e >> 3) ^ ((gp >> 1) & 3)) << 3) + (e & 7)] = (_Float16)hv;
                }
            }
        }
        asm volatile("" ::: "memory");   // keep W2 reads after W1 writes
        #pragma unroll
        for (int mt2 = 0; mt2 < 2; mt2++) {
            const int mt = 2 * wid + mt2;
            const int row = 16 * mt + l15;
            h8 a2 = *(const h8*)&s_h1[row][((lk ^ ((row >> 1) & 3)) << 3)];
            #pragma unroll
            for (int nt = 0; nt < 4; nt++) {
                const int c = 16 * nt + l15;
                h8 w20 = *(const h8*)&w2t[0][c][8 * lk];
                h8 w21 = *(const h8*)&w2t[1][c][8 * lk];
                f4 e0 = __builtin_amdgcn_mfma_f32_16x16x32_f16(a2, w20, zf4, 0, 0, 0);
                f4 e1 = __builtin_amdgcn_mfma_f32_16x16x32_f16(a2, w21, zf4, 0, 0, 0);
                #pragma unroll
                for (int r = 0; r < 4; r++) {
                    int gp = 16 * mt + 4 * lk + r;
                    bool is0 = (s_nbr[t128 + gp] < n1);
                    float ev = fast_tanh((is0 ? e0[r] : e1[r]) + (is0 ? b2r[0][nt] : b2r[1][nt]));
                    s_ef[nt][gp >> 5][l15 + 16 * ((gp & 31) >> 3)][gp & 7] = (_Float16)ev;
                }
            }
        }
        __syncthreads();   // B3: s_ef ready (cross-wave)

        // ---- stage 2: G[8pad16][64] += coef[8][128] @ e[128][64] ----
        // coef rows 0-3 = atom A, rows 4-7 = atom B (list is [A-pairs | B-pairs])
        #pragma unroll
        for (int ks = 0; ks < 4; ks++) {
            const int s = t128 + 32 * ks;
            h8 ac = {};
            if (l15 < 8) {
                const bool rowA = l15 < 4;
                const int  cr   = rowA ? l15 : (l15 - 4);
                const bool allA = (s + 31) < cntA;
                const bool allB = s >= cntA;
                if ((allA && rowA) || (allB && !rowA)) {
                    ac = *(const h8*)&s_cf[cr][s + 8 * lk];
                } else if (!allA && !allB) {
                    #pragma unroll
                    for (int r = 0; r < 8; r++) {
                        int p = s + 8 * lk + r;
                        bool isA = p < cntA;
                        if (isA == rowA) ac[r] = s_cf[cr][p];
                    }
                }
            }
            h8 eb = *(const h8*)&s_ef[wid][ks][lane][0];
            gacc = __builtin_amdgcn_mfma_f32_16x16x32_f16(ac, eb, gacc, 0, 0, 0);
        }
    }

    // ---- epilogue: rows 0-3 (lk=0) = atom A, rows 4-7 (lk=1) = atom B ----
    if (lk < 2) {
        float* sg = &s_g4[lk][0];
        #pragma unroll
        for (int r = 0; r < 4; r++) {
            float gv = gacc[r] * (1.0f / 64.0f);
            if (r == 0) gv += Gbias[16 * wid + l15];
            sg[r * 64 + 16 * wid + l15] = gv;
        }
    }
    __syncthreads();
    #pragma unroll
    for (int at = 0; at < 2; at++) {
        const float* sg = &s_g4[at][0];
        h2v* outp = feat + (size_t)(2 * nb + at) * 512;
        #pragma unroll
        for (int q = 0; q < 2; q++) {
            int o2 = tid + 256 * q;
            int a = o2 >> 5, c = (2 * o2) & 63;
            float ga0 = sg[a],       ga1 = sg[64 + a];
            float ga2 = sg[128 + a], ga3 = sg[192 + a];
            float s0 = ga0 * sg[c];
            s0 = fmaf(ga1, sg[64 + c],  s0);
            s0 = fmaf(ga2, sg[128 + c], s0);
            s0 = fmaf(ga3, sg[192 + c], s0);
            float s1 = ga0 * sg[c + 1];
            s1 = fmaf(ga1, sg[64 + c + 1],  s1);
            s1 = fmaf(ga2, sg[128 + c + 1], s1);
            s1 = fmaf(ga3, sg[192 + c + 1], s1);
            outp[o2] = pkh(s0, s1);
        }
    }
}

// ---- Kernel 2: fit net, 64 blocks x 16 atoms, direct-from-L2 fragments ----
__global__ __launch_bounds__(512, 1) void k_fit(
    const _Float16* __restrict__ featf, const _Float16* __restrict__ W0ht,
    const _Float16* __restrict__ W1ht,
    const float* __restrict__ b0, const float* __restrict__ b1,
    const float* __restrict__ W2, const float* __restrict__ b2,
    const float* __restrict__ Ebias, const int* __restrict__ n1p,
    unsigned int* __restrict__ counter, float* __restrict__ slots,
    float* __restrict__ out)
{
    __shared__ float s_red[4][2][16][64];              // 32 KB  K-quarter partials
    __shared__ __align__(16) _Float16 s_hd[16][128];   // 4 KB   layer-0 out (swz)
    __shared__ float s_sum[16][32];                    // 2 KB

    const int tid = threadIdx.x;
    const int lane = tid & 63, w = tid >> 6;
    const int kq = w >> 1, ch = w & 1;
    const int l15 = lane & 15, lk = lane >> 4;
    const int n0 = blockIdx.x * 16;
    const int ia = (n0 >= *n1p) ? 1 : 0;
    const f4 zf4 = {0.0f, 0.0f, 0.0f, 0.0f};

    // ---- layer 0: rows=16 atoms, wave=(ch: 64 cols, kq: K=256) ----
    const _Float16* Ap = featf + (size_t)(n0 + l15) * 1024 + kq * 256;
    const _Float16* B0 = W0ht + (size_t)ia * 131072 + kq * 256;
    f4 acc[4] = {zf4, zf4, zf4, zf4};
    #pragma unroll
    for (int ks = 0; ks < 8; ks++) {
        h8 a = *(const h8*)(Ap + ks * 32 + 8 * lk);
        #pragma unroll
        for (int nt = 0; nt < 4; nt++) {
            const int c = ch * 64 + nt * 16 + l15;
            h8 b = *(const h8*)(B0 + (size_t)c * 1024 + ks * 32 + 8 * lk);
            acc[nt] = __builtin_amdgcn_mfma_f32_16x16x32_f16(a, b, acc[nt], 0, 0, 0);
        }
    }
    #pragma unroll
    for (int nt = 0; nt < 4; nt++)
        #pragma unroll
        for (int r = 0; r < 4; r++)
            s_red[kq][ch][4 * lk + r][nt * 16 + l15] = acc[nt][r];
    __syncthreads();

    // ---- reduce over kq + bias + tanh -> s_hd (f16, unit-swizzled) ----
    {
        const int row = tid >> 5, c0 = (tid & 31) * 4;
        const int chh = c0 >> 6, cl = c0 & 63;
        f4 v = *(const f4*)&s_red[0][chh][row][cl];
        v += *(const f4*)&s_red[1][chh][row][cl];
        v += *(const f4*)&s_red[2][chh][row][cl];
        v += *(const f4*)&s_red[3][chh][row][cl];
        #pragma unroll
        for (int q = 0; q < 4; q++) {
            int c = c0 + q;
            float h = fast_tanh(v[q] + b0[ia * 128 + c]);
            s_hd[row][(((c >> 3) ^ row) << 3) + (c & 7)] = (_Float16)h;
        }
    }
    __syncthreads();

    // ---- layer 1: wave=(ch: 64 cols, kq: K=32) ----
    f4 acc1[4] = {zf4, zf4, zf4, zf4};
    {
        h8 a = *(const h8*)&s_hd[l15][(((4 * kq + lk) ^ l15) & 15) << 3];
        const _Float16* B1 = W1ht + (size_t)ia * 16384 + kq * 32;
        #pragma unroll
        for (int nt = 0; nt < 4; nt++) {
            const int c = ch * 64 + nt * 16 + l15;
            h8 b = *(const h8*)(B1 + (size_t)c * 128 + 8 * lk);
            acc1[nt] = __builtin_amdgcn_mfma_f32_16x16x32_f16(a, b, zf4, 0, 0, 0);
        }
    }
    #pragma unroll
    for (int nt = 0; nt < 4; nt++)
        #pragma unroll
        for (int r = 0; r < 4; r++)
            s_red[kq][ch][4 * lk + r][nt * 16 + l15] = acc1[nt][r];
    __syncthreads();

    // ---- final: reduce + bias + tanh, x W2, row/block sums (deterministic) --
    {
        const int row = tid >> 5, c0 = (tid & 31) * 4;
        const int chh = c0 >> 6, cl = c0 & 63;
        f4 v = *(const f4*)&s_red[0][chh][row][cl];
        v += *(const f4*)&s_red[1][chh][row][cl];
        v += *(const f4*)&s_red[2][chh][row][cl];
        v += *(const f4*)&s_red[3][chh][row][cl];
        float pv = 0.0f;
        #pragma unroll
        for (int q = 0; q < 4; q++) {
            int c = c0 + q;
            pv += fast_tanh(v[q] + b1[ia * 128 + c]) * W2[ia * 128 + c];
        }
        s_sum[row][tid & 31] = pv;
    }
    __syncthreads();
    if (w == 0) {
        const int row = lane >> 2, g = lane & 3;
        float s = 0.0f;
        #pragma unroll
        for (int i = 0; i < 8; i++) s += s_sum[row][8 * g + i];
        s += __shfl_xor(s, 1);  s += __shfl_xor(s, 2);   // across g
        s += __shfl_xor(s, 4);  s += __shfl_xor(s, 8);   // across rows
        s += __shfl_xor(s, 16); s += __shfl_xor(s, 32);
        if (lane == 0) {
            float e = s + 16.0f * (b2[ia] + Ebias[ia]);
            slots[blockIdx.x] = e;
            __threadfence();
            unsigned int old = atomicAdd(counter, 1u);
            if (old == 63u) {
                __threadfence();
                float tot = 0.0f;
                for (int i = 0; i < 64; i++)
                    tot += __hip_atomic_load(&slots[i], __ATOMIC_RELAXED, __HIP_MEMORY_SCOPE_AGENT);
                out[0] = tot;
            }
        }
    }
}

extern "C" void kernel_launch(void* const* d_in, const int* in_sizes, int n_in,
                              void* d_out, int out_size, void* d_ws, size_t ws_size,
                              hipStream_t stream) {
    const float* coord   = (const float*)d_in[0];
    const float* box     = (const float*)d_in[1];
    const float* srmean  = (const float*)d_in[2];
    const float* srstd   = (const float*)d_in[3];
    const float* xrsrstd = (const float*)d_in[4];
    const float* Gbias   = (const float*)d_in[5];
    const float* Ebias   = (const float*)d_in[6];
    const float* eW0     = (const float*)d_in[7];
    const float* eb0     = (const float*)d_in[8];
    const float* eW1     = (const float*)d_in[9];
    const float* eb1     = (const float*)d_in[10];
    const float* eW2     = (const float*)d_in[11];
    const float* eb2     = (const float*)d_in[12];
    const float* fW0     = (const float*)d_in[13];
    const float* fb0     = (const float*)d_in[14];
    const float* fW1     = (const float*)d_in[15];
    const float* fb1     = (const float*)d_in[16];
    const float* fW2     = (const float*)d_in[17];
    const float* fb2     = (const float*)d_in[18];
    const int*   n1p     = (const int*)d_in[19];

    const int N = in_sizes[0] / 3;          // 1024
    h2v*      featbuf = (h2v*)d_ws;                                       // 2 MB
    _Float16* W0ht = (_Float16*)((char*)d_ws + (size_t)2 * 1024 * 1024);  // 512 KB
    _Float16* W1ht = W0ht + 2 * 131072;                                   // 64 KB
    char* tail = (char*)d_ws + (size_t)(2 * 1024 + 512 + 64) * 1024;
    unsigned int* counter = (unsigned int*)tail;
    float*        slots   = (float*)(tail + 64);

    k_embed<<<N / 2 + 288, 256, 0, stream>>>(coord, box, srmean, srstd, xrsrstd,
                                             Gbias, eW0, eb0, eW1, eb1, eW2, eb2,
                                             n1p, fW0, fW1, featbuf, W0ht, W1ht,
                                             counter, N);
    k_fit<<<N / 16, 512, 0, stream>>>((const _Float16*)featbuf, W0ht, W1ht,
                                      fb0, fb1, fW2, fb2, Ebias, n1p,
                                      counter, slots, (float*)d_out);
}